// Round 2
// baseline (614.630 us; speedup 1.0000x reference)
//
#include <hip/hip_runtime.h>
#include <cstdint>
#include <cstddef>

#define N 8192
#define D 128
#define KNN 20
#define NC 10
#define CAPB 448          // max survivor buffer capacity per row (register-limited in k_sel2)
#define ZTH 2.1f          // threshold z-score (expected ~100 survivors/row)
constexpr float EPS = 1e-10f;

typedef __attribute__((ext_vector_type(8))) short short8;
typedef __attribute__((ext_vector_type(4))) float f32x4;

// bf16 round-to-nearest-even, pure bit ops
__device__ inline unsigned short f32_to_bf16_rne(float x) {
    unsigned u = __float_as_uint(x);
    unsigned r = u + 0x7FFFu + ((u >> 16) & 1u);
    return (unsigned short)(r >> 16);
}
__device__ inline float bf16_to_f32(unsigned short h) {
    return __uint_as_float((unsigned)h << 16);
}
__device__ inline unsigned long long pack_key(float d, int j) {
    return ((unsigned long long)__float_as_uint(d) << 14) | (unsigned long long)(j + 1);
}

// ---------------- K1: squared norms (exact fp32) ----------------
__global__ void k_sqnorm(const float* __restrict__ X, float* __restrict__ sq) {
    int row = blockIdx.x;
    int lane = threadIdx.x;
    const float2* X2 = (const float2*)(X + (size_t)row * D);
    float2 a = X2[lane];
    float s = a.x * a.x + a.y * a.y;
    #pragma unroll
    for (int off = 32; off; off >>= 1) s += __shfl_down(s, off, 64);
    if (lane == 0) sq[row] = s;
}

// ---------------- K2: split X into bf16 hi + lo ----------------
__global__ void k_split(const float* __restrict__ X, unsigned short* __restrict__ Xhi,
                        unsigned short* __restrict__ Xlo) {
    int i = blockIdx.x * 256 + threadIdx.x;     // 1M elems / 4
    const float4* X4 = (const float4*)X;
    float4 x = X4[i];
    unsigned short h[4], l[4];
    float xs[4] = {x.x, x.y, x.z, x.w};
    #pragma unroll
    for (int q = 0; q < 4; ++q) {
        h[q] = f32_to_bf16_rne(xs[q]);
        float hf = bf16_to_f32(h[q]);
        l[q] = f32_to_bf16_rne(xs[q] - hf);
    }
    *(ushort4*)&Xhi[(size_t)i * 4] = make_ushort4(h[0], h[1], h[2], h[3]);
    *(ushort4*)&Xlo[(size_t)i * 4] = make_ushort4(l[0], l[1], l[2], l[3]);
}

// ---------------- K2b: data moments (col sums, sum sq, sum sq^2) ----------------
__global__ __launch_bounds__(128) void k_moments(const float* __restrict__ X,
                                                 const float* __restrict__ sq,
                                                 float* __restrict__ m1,
                                                 float* __restrict__ msc) {
    int b = blockIdx.x, t = threadIdx.x;        // 128 blocks x 128 threads, 64 rows each
    int r0 = b * 64;
    float s1 = 0.f;
    for (int r = 0; r < 64; ++r) s1 += X[(size_t)(r0 + r) * D + t];
    atomicAdd(&m1[t], s1);
    if (t < 64) {                               // wave 0
        float s = sq[r0 + t];
        float ss1 = s, ss2 = s * s;
        #pragma unroll
        for (int off = 32; off; off >>= 1) {
            ss1 += __shfl_down(ss1, off, 64);
            ss2 += __shfl_down(ss2, off, 64);
        }
        if (t == 0) { atomicAdd(&msc[0], ss1); atomicAdd(&msc[1], ss2); }
    }
}

// ---------------- K2c: per-row analytic survivor threshold ----------------
// mu_i = sq_i + E[sq] - 2 x_i . mean(x);  var_i = Var[sq] + 4 sq_i  (Cov ~ I)
__global__ void k_thresh(const float* __restrict__ X, const float* __restrict__ sq,
                         const float* __restrict__ m1, const float* __restrict__ msc,
                         float* __restrict__ T) {
    int row = blockIdx.x, lane = threadIdx.x;   // 64 lanes
    const float2* X2 = (const float2*)(X + (size_t)row * D);
    const float2* M2 = (const float2*)m1;
    float2 a = X2[lane], m = M2[lane];
    float dotp = a.x * m.x + a.y * m.y;
    #pragma unroll
    for (int off = 32; off; off >>= 1) dotp += __shfl_down(dotp, off, 64);
    if (lane == 0) {
        const float invN = 1.f / N;
        float Esq   = msc[0] * invN;
        float Esq2  = msc[1] * invN;
        float varSq = fmaxf(Esq2 - Esq * Esq, 0.f);
        float s  = sq[row];
        float mu = s + Esq - 2.f * dotp * invN;
        float var = varSq + 4.f * s;
        T[row] = mu - ZTH * sqrtf(var);
    }
}

// ---------------- K3: fused MFMA distance tile + survivor scatter ------------
// Upper-triangle tiles only (blockIdx.x >= 2*blockIdx.y); element guard j >= i;
// each surviving pair pushed to both rows' buffers. d2 accumulation order is
// identical to the previously verified k_distm (bit-identical values).
#define ASTRIDE 40   // bf16 elems per LDS row (32 data + 8 pad); 80 B, 16B-aligned
__global__ __launch_bounds__(256) void k_distf(
        const unsigned short* __restrict__ Xhi, const unsigned short* __restrict__ Xlo,
        const float* __restrict__ sqn, const float* __restrict__ Tthr,
        int* __restrict__ cnt, unsigned long long* __restrict__ rowbuf, int capb) {
    if (blockIdx.x < blockIdx.y * 2) return;    // strictly-below-diagonal tile: skip

    __shared__ unsigned short sAhi[256 * ASTRIDE];
    __shared__ unsigned short sAlo[256 * ASTRIDE];
    __shared__ unsigned short sBhi[128 * ASTRIDE];
    __shared__ unsigned short sBlo[128 * ASTRIDE];

    const int t    = threadIdx.x;
    const int lane = t & 63;
    const int w    = t >> 6;
    const int wr   = w >> 1;          // 0..1 : 128-row half
    const int wc   = w & 1;           // 0..1 : 64-col half
    const int lrow = lane & 15;       // fragment row within 16
    const int lkg  = lane >> 4;       // 0..3 : k-group (8 bf16 each)

    const int rowTile = blockIdx.y * 256;
    const int colTile = blockIdx.x * 128;

    f32x4 acc[8][4];
    #pragma unroll
    for (int i = 0; i < 8; ++i)
        #pragma unroll
        for (int j = 0; j < 4; ++j) acc[i][j] = (f32x4){0.f, 0.f, 0.f, 0.f};

    for (int kc = 0; kc < 4; ++kc) {            // four K-chunks of 32
        const int kb = kc * 32;
        __syncthreads();
        #pragma unroll
        for (int p = 0; p < 4; ++p) {           // stage A (256 rows)
            int u = t + 256 * p, r = u >> 2, c = u & 3;
            size_t g = (size_t)(rowTile + r) * 128 + kb + c * 8;
            *(uint4*)&sAhi[r * ASTRIDE + c * 8] = *(const uint4*)&Xhi[g];
            *(uint4*)&sAlo[r * ASTRIDE + c * 8] = *(const uint4*)&Xlo[g];
        }
        #pragma unroll
        for (int p = 0; p < 2; ++p) {           // stage B (128 rows)
            int u = t + 256 * p, r = u >> 2, c = u & 3;
            size_t g = (size_t)(colTile + r) * 128 + kb + c * 8;
            *(uint4*)&sBhi[r * ASTRIDE + c * 8] = *(const uint4*)&Xhi[g];
            *(uint4*)&sBlo[r * ASTRIDE + c * 8] = *(const uint4*)&Xlo[g];
        }
        __syncthreads();

        short8 a[8], b[4];
        // pass 1: hi . hi
        #pragma unroll
        for (int i = 0; i < 8; ++i)
            a[i] = *(const short8*)&sAhi[(wr * 128 + 16 * i + lrow) * ASTRIDE + lkg * 8];
        #pragma unroll
        for (int j = 0; j < 4; ++j)
            b[j] = *(const short8*)&sBhi[(wc * 64 + 16 * j + lrow) * ASTRIDE + lkg * 8];
        #pragma unroll
        for (int i = 0; i < 8; ++i)
            #pragma unroll
            for (int j = 0; j < 4; ++j)
                acc[i][j] = __builtin_amdgcn_mfma_f32_16x16x32_bf16(a[i], b[j], acc[i][j], 0, 0, 0);
        // pass 2: hi . lo
        #pragma unroll
        for (int j = 0; j < 4; ++j)
            b[j] = *(const short8*)&sBlo[(wc * 64 + 16 * j + lrow) * ASTRIDE + lkg * 8];
        #pragma unroll
        for (int i = 0; i < 8; ++i)
            #pragma unroll
            for (int j = 0; j < 4; ++j)
                acc[i][j] = __builtin_amdgcn_mfma_f32_16x16x32_bf16(a[i], b[j], acc[i][j], 0, 0, 0);
        // pass 3: lo . hi
        #pragma unroll
        for (int i = 0; i < 8; ++i)
            a[i] = *(const short8*)&sAlo[(wr * 128 + 16 * i + lrow) * ASTRIDE + lkg * 8];
        #pragma unroll
        for (int j = 0; j < 4; ++j)
            b[j] = *(const short8*)&sBhi[(wc * 64 + 16 * j + lrow) * ASTRIDE + lkg * 8];
        #pragma unroll
        for (int i = 0; i < 8; ++i)
            #pragma unroll
            for (int j = 0; j < 4; ++j)
                acc[i][j] = __builtin_amdgcn_mfma_f32_16x16x32_bf16(a[i], b[j], acc[i][j], 0, 0, 0);
    }

    // epilogue: C/D layout col=lane&15, row=(lane>>4)*4+reg  [m89/m91]
    float sqb[4], Tb[4]; int gcol[4];
    #pragma unroll
    for (int j = 0; j < 4; ++j) {
        gcol[j] = colTile + wc * 64 + 16 * j + lrow;
        sqb[j]  = sqn[gcol[j]];
        Tb[j]   = Tthr[gcol[j]];
    }
    #pragma unroll
    for (int i = 0; i < 8; ++i) {
        int gr0 = rowTile + wr * 128 + 16 * i + lkg * 4;
        #pragma unroll
        for (int q = 0; q < 4; ++q) {
            int gi = gr0 + q;
            float sa = sqn[gi];
            float Ti = Tthr[gi];
            #pragma unroll
            for (int j = 0; j < 4; ++j) {
                float d = fmaxf(fmaf(-2.f, acc[i][j][q], sa + sqb[j]), 0.f);
                int gj = gcol[j];
                if (gj >= gi && d < Ti) {
                    int p = atomicAdd(&cnt[gi], 1);
                    if (p < capb) rowbuf[(size_t)gi * capb + p] = pack_key(d, gj);
                }
                if (gj > gi && d < Tb[j]) {
                    int p = atomicAdd(&cnt[gj], 1);
                    if (p < capb) rowbuf[(size_t)gj * capb + p] = pack_key(d, gi);
                }
            }
        }
    }
}

// ---------------- K4: exact top-20 from survivor buffer ----------------
__global__ __launch_bounds__(64) void k_sel2(const unsigned long long* __restrict__ rowbuf,
                                             const int* __restrict__ cnt,
                                             int* __restrict__ knn_idx,
                                             float* __restrict__ density,
                                             int* __restrict__ flagged,
                                             int* __restrict__ nflag, int capb) {
    int row = blockIdx.x, t = threadIdx.x;
    int n = cnt[row];
    if (n < KNN || n > capb) {                  // model miss: exact fallback handles it
        if (t == 0) { int p = atomicAdd(nflag, 1); flagged[p] = row; }
        return;
    }
    const unsigned long long* rb = rowbuf + (size_t)row * capb;
    unsigned long long v[7];                    // 7*64 = 448 >= capb
    #pragma unroll
    for (int k = 0; k < 7; ++k) { int idx = t + 64 * k; v[k] = idx < n ? rb[idx] : ~0ull; }
    unsigned long long last = 0ull;
    float sumd = 0.f;
    for (int r = 0; r < KNN; ++r) {
        unsigned long long m = ~0ull;
        #pragma unroll
        for (int k = 0; k < 7; ++k) if (v[k] > last && v[k] < m) m = v[k];
        #pragma unroll
        for (int off = 32; off; off >>= 1) {
            unsigned long long o = __shfl_down(m, off, 64);
            if (o < m) m = o;
        }
        m = __shfl(m, 0, 64);
        last = m;
        if (t == 0) {
            int j = (int)(m & 16383ull) - 1;
            if (j < 0) j = 0; if (j >= N) j = N - 1;
            knn_idx[(size_t)row * KNN + r] = j;
            sumd += sqrtf(__uint_as_float((unsigned)(m >> 14)));
        }
    }
    if (t == 0) density[row] = 1.f / (sumd * (1.f / KNN) + EPS);
}

// ---------------- K4b: exact fp32 brute-force fallback for flagged rows -------
__global__ __launch_bounds__(256) void k_fallback(const float* __restrict__ X,
                                                  const float* __restrict__ sq,
                                                  const int* __restrict__ nflag,
                                                  const int* __restrict__ flagged,
                                                  int* __restrict__ knn_idx,
                                                  float* __restrict__ density) {
    __shared__ float xr[D];
    __shared__ unsigned long long red[256];
    int t = threadIdx.x;
    int nf = *nflag;
    for (int f = blockIdx.x; f < nf; f += gridDim.x) {
        int row = flagged[f];
        __syncthreads();
        if (t < D) xr[t] = X[(size_t)row * D + t];
        __syncthreads();
        float sqr = sq[row];
        unsigned long long keys[32];
        for (int i = 0; i < 32; ++i) {
            int col = t + 256 * i;
            const float4* cp = (const float4*)(X + (size_t)col * D);
            float dot = 0.f;
            #pragma unroll
            for (int d4 = 0; d4 < 32; ++d4) {
                float4 c = cp[d4];
                float4 x = *(const float4*)&xr[d4 * 4];
                dot = fmaf(c.x, x.x, dot); dot = fmaf(c.y, x.y, dot);
                dot = fmaf(c.z, x.z, dot); dot = fmaf(c.w, x.w, dot);
            }
            float d2 = fmaxf(sqr + sq[col] - 2.f * dot, 0.f);
            keys[i] = pack_key(d2, col);
        }
        unsigned long long last = 0ull;
        float sumd = 0.f;
        for (int r = 0; r < KNN; ++r) {
            unsigned long long m = ~0ull;
            #pragma unroll
            for (int i = 0; i < 32; ++i) if (keys[i] > last && keys[i] < m) m = keys[i];
            red[t] = m; __syncthreads();
            for (int s = 128; s; s >>= 1) {
                if (t < s && red[t + s] < red[t]) red[t] = red[t + s];
                __syncthreads();
            }
            m = red[0]; __syncthreads();
            last = m;
            if (t == 0) {
                int j = (int)(m & 16383ull) - 1;
                if (j < 0) j = 0; if (j >= N) j = N - 1;
                knn_idx[(size_t)row * KNN + r] = j;
                sumd += sqrtf(__uint_as_float((unsigned)(m >> 14)));
            }
        }
        if (t == 0) density[row] = 1.f / (sumd * (1.f / KNN) + EPS);
    }
}

// ---------------- K5: scatter knn + rnn (deduped) contributions ----------------
__global__ void k_scatter(const int* __restrict__ knn_idx, const float* __restrict__ density,
                          float* __restrict__ numer, float* __restrict__ cntb) {
    int p = blockIdx.x * 256 + threadIdx.x;
    if (p >= N * KNN) return;
    int i = p / KNN;
    int j = knn_idx[p];
    atomicAdd(&numer[i], density[j]);
    atomicAdd(&cntb[i], 1.f);
    bool found = false;
    const int* kj = knn_idx + (size_t)j * KNN;
    #pragma unroll
    for (int m = 0; m < KNN; ++m) found |= (kj[m] == i);
    if (!found) {
        atomicAdd(&numer[j], density[i]);
        atomicAdd(&cntb[j], 1.f);
    }
}

// ---------------- K6: scores, flags, class preds ----------------
__global__ void k_final(const float* __restrict__ density, const float* __restrict__ numer,
                        const float* __restrict__ cntb, const float* __restrict__ logits,
                        float* __restrict__ out) {
    int i = blockIdx.x * 256 + threadIdx.x;
    if (i >= N) return;
    float c     = fmaxf(cntb[i], 1.f);
    float avg   = numer[i] / c;
    float score = -(density[i] / (avg + EPS));
    out[i] = score;
    bool flag = score < -0.5f;
    out[N + i] = flag ? 1.f : 0.f;
    const float* lg = logits + (size_t)i * NC;
    float best = lg[0]; int bi = 0;
    #pragma unroll
    for (int k = 1; k < NC; ++k) { float x = lg[k]; if (x > best) { best = x; bi = k; } }
    out[2 * N + i] = flag ? -1.f : (float)bi;
}

extern "C" void kernel_launch(void* const* d_in, const int* in_sizes, int n_in,
                              void* d_out, int out_size, void* d_ws, size_t ws_size,
                              hipStream_t stream) {
    const float* X      = (const float*)d_in[0];
    const float* logits = (const float*)d_in[1];
    float* out = (float*)d_out;

    char* w = (char*)d_ws;
    auto alloc = [&](size_t bytes) { char* p = w; w += (bytes + 255) & ~(size_t)255; return p; };
    float* sq      = (float*)alloc((size_t)N * 4);
    float* density = (float*)alloc((size_t)N * 4);
    float* numer   = (float*)alloc((size_t)N * 4);
    float* cntb    = (float*)alloc((size_t)N * 4);
    int*   knn     = (int*)alloc((size_t)N * KNN * 4);
    unsigned short* Xhi = (unsigned short*)alloc((size_t)N * D * 2);
    unsigned short* Xlo = (unsigned short*)alloc((size_t)N * D * 2);
    float* Tthr    = (float*)alloc((size_t)N * 4);
    float* m1      = (float*)alloc((size_t)(D + 2) * 4);   // col sums + {sum sq, sum sq^2}
    int*   cnt     = (int*)alloc((size_t)N * 4);
    int*   flagged = (int*)alloc((size_t)N * 4);
    int*   nflag   = (int*)alloc(256);

    // survivor buffer: sized from the ACTUAL remaining workspace (never OOB).
    unsigned long long* rowbuf = (unsigned long long*)w;
    size_t used  = (size_t)(w - (char*)d_ws);
    size_t avail = ws_size > used ? ws_size - used : 0;
    int capb = (int)(avail / ((size_t)N * 8));
    if (capb > CAPB) capb = CAPB;               // k_sel2 register budget (7*64)
    if (capb < 1) capb = 1;                     // degenerate: all rows -> exact fallback

    hipMemsetAsync(numer, 0, (size_t)N * 4, stream);
    hipMemsetAsync(cntb,  0, (size_t)N * 4, stream);
    hipMemsetAsync(m1,    0, (size_t)(D + 2) * 4, stream);
    hipMemsetAsync(cnt,   0, (size_t)N * 4, stream);
    hipMemsetAsync(nflag, 0, 4, stream);

    k_sqnorm <<<N, 64, 0, stream>>>(X, sq);
    k_split  <<<(N * D / 4 + 255) / 256, 256, 0, stream>>>(X, Xhi, Xlo);
    k_moments<<<128, 128, 0, stream>>>(X, sq, m1, m1 + D);
    k_thresh <<<N, 64, 0, stream>>>(X, sq, m1, m1 + D, Tthr);

    k_distf  <<<dim3(64, 32), 256, 0, stream>>>(Xhi, Xlo, sq, Tthr, cnt, rowbuf, capb);

    k_sel2    <<<N, 64, 0, stream>>>(rowbuf, cnt, knn, density, flagged, nflag, capb);
    k_fallback<<<64, 256, 0, stream>>>(X, sq, nflag, flagged, knn, density);

    k_scatter<<<(N * KNN + 255) / 256, 256, 0, stream>>>(knn, density, numer, cntb);
    k_final  <<<(N + 255) / 256, 256, 0, stream>>>(density, numer, cntb, logits, out);
}

// Round 3
// 414.675 us; speedup vs baseline: 1.4822x; 1.4822x over previous
//
#include <hip/hip_runtime.h>
#include <cstdint>
#include <cstddef>

#define N 8192
#define D 128
#define KNN 20
#define NC 10
#define CAPB 448          // max survivor buffer capacity per row (register-limited in k_sel2)
#define ZTH 2.1f          // threshold z-score (expected ~120 survivors/row)
constexpr float EPS = 1e-10f;

typedef __attribute__((ext_vector_type(8))) short short8;
typedef __attribute__((ext_vector_type(4))) float f32x4;

// bf16 round-to-nearest-even, pure bit ops
__device__ inline unsigned short f32_to_bf16_rne(float x) {
    unsigned u = __float_as_uint(x);
    unsigned r = u + 0x7FFFu + ((u >> 16) & 1u);
    return (unsigned short)(r >> 16);
}
__device__ inline float bf16_to_f32(unsigned short h) {
    return __uint_as_float((unsigned)h << 16);
}
__device__ inline unsigned long long pack_key(float d, int j) {
    return ((unsigned long long)__float_as_uint(d) << 14) | (unsigned long long)(j + 1);
}

// ---------------- K1: squared norms (exact fp32) ----------------
__global__ void k_sqnorm(const float* __restrict__ X, float* __restrict__ sq) {
    int row = blockIdx.x;
    int lane = threadIdx.x;
    const float2* X2 = (const float2*)(X + (size_t)row * D);
    float2 a = X2[lane];
    float s = a.x * a.x + a.y * a.y;
    #pragma unroll
    for (int off = 32; off; off >>= 1) s += __shfl_down(s, off, 64);
    if (lane == 0) sq[row] = s;
}

// ---------------- K2: split X into bf16 hi + lo ----------------
__global__ void k_split(const float* __restrict__ X, unsigned short* __restrict__ Xhi,
                        unsigned short* __restrict__ Xlo) {
    int i = blockIdx.x * 256 + threadIdx.x;     // 1M elems / 4
    const float4* X4 = (const float4*)X;
    float4 x = X4[i];
    unsigned short h[4], l[4];
    float xs[4] = {x.x, x.y, x.z, x.w};
    #pragma unroll
    for (int q = 0; q < 4; ++q) {
        h[q] = f32_to_bf16_rne(xs[q]);
        float hf = bf16_to_f32(h[q]);
        l[q] = f32_to_bf16_rne(xs[q] - hf);
    }
    *(ushort4*)&Xhi[(size_t)i * 4] = make_ushort4(h[0], h[1], h[2], h[3]);
    *(ushort4*)&Xlo[(size_t)i * 4] = make_ushort4(l[0], l[1], l[2], l[3]);
}

// ---------------- K2b: data moments (col sums, sum sq, sum sq^2) ----------------
__global__ __launch_bounds__(128) void k_moments(const float* __restrict__ X,
                                                 const float* __restrict__ sq,
                                                 float* __restrict__ m1,
                                                 float* __restrict__ msc) {
    int b = blockIdx.x, t = threadIdx.x;        // 128 blocks x 128 threads, 64 rows each
    int r0 = b * 64;
    float s1 = 0.f;
    for (int r = 0; r < 64; ++r) s1 += X[(size_t)(r0 + r) * D + t];
    atomicAdd(&m1[t], s1);
    if (t < 64) {                               // wave 0
        float s = sq[r0 + t];
        float ss1 = s, ss2 = s * s;
        #pragma unroll
        for (int off = 32; off; off >>= 1) {
            ss1 += __shfl_down(ss1, off, 64);
            ss2 += __shfl_down(ss2, off, 64);
        }
        if (t == 0) { atomicAdd(&msc[0], ss1); atomicAdd(&msc[1], ss2); }
    }
}

// ---------------- K2c: per-row analytic survivor threshold ----------------
// mu_i = sq_i + E[sq] - 2 x_i . mean(x);  var_i = Var[sq] + 4 sq_i  (exact for iid gauss)
__global__ void k_thresh(const float* __restrict__ X, const float* __restrict__ sq,
                         const float* __restrict__ m1, const float* __restrict__ msc,
                         float* __restrict__ T) {
    int row = blockIdx.x, lane = threadIdx.x;   // 64 lanes
    const float2* X2 = (const float2*)(X + (size_t)row * D);
    const float2* M2 = (const float2*)m1;
    float2 a = X2[lane], m = M2[lane];
    float dotp = a.x * m.x + a.y * m.y;
    #pragma unroll
    for (int off = 32; off; off >>= 1) dotp += __shfl_down(dotp, off, 64);
    if (lane == 0) {
        const float invN = 1.f / N;
        float Esq   = msc[0] * invN;
        float Esq2  = msc[1] * invN;
        float varSq = fmaxf(Esq2 - Esq * Esq, 0.f);
        float s  = sq[row];
        float mu = s + Esq - 2.f * dotp * invN;
        float var = varSq + 4.f * s;
        T[row] = mu - ZTH * sqrtf(var);
    }
}

// ---------------- K3: fused MFMA distance tile + survivor scatter ------------
// Upper-triangle tiles only (blockIdx.x >= 2*blockIdx.y); element guard j >= i.
// Survivors are aggregated in a block-local LDS list first (R2 post-mortem:
// per-lane global atomicAdd-with-return in the epilogue serialized ~200K
// cyc/block -> 463us; LDS aggregation cuts dependent global round-trips
// per wave from ~160 to ~5), then flushed cooperatively.
#define ASTRIDE 40   // bf16 elems per LDS row (32 data + 8 pad); 80 B, 16B-aligned
#define LCAP 2560    // LDS survivor-list slots (overlays sAhi: 20480 B / 8)
__global__ __launch_bounds__(256) void k_distf(
        const unsigned short* __restrict__ Xhi, const unsigned short* __restrict__ Xlo,
        const float* __restrict__ sqn, const float* __restrict__ Tthr,
        int* __restrict__ cnt, unsigned long long* __restrict__ rowbuf, int capb) {
    if (blockIdx.x < blockIdx.y * 2) return;    // strictly-below-diagonal tile: skip

    __shared__ alignas(16) unsigned short sAhi[256 * ASTRIDE];
    __shared__ unsigned short sAlo[256 * ASTRIDE];
    __shared__ unsigned short sBhi[128 * ASTRIDE];
    __shared__ unsigned short sBlo[128 * ASTRIDE];
    __shared__ int lc;

    const int t    = threadIdx.x;
    const int lane = t & 63;
    const int w    = t >> 6;
    const int wr   = w >> 1;          // 0..1 : 128-row half
    const int wc   = w & 1;           // 0..1 : 64-col half
    const int lrow = lane & 15;       // fragment row within 16
    const int lkg  = lane >> 4;       // 0..3 : k-group (8 bf16 each)

    const int rowTile = blockIdx.y * 256;
    const int colTile = blockIdx.x * 128;

    f32x4 acc[8][4];
    #pragma unroll
    for (int i = 0; i < 8; ++i)
        #pragma unroll
        for (int j = 0; j < 4; ++j) acc[i][j] = (f32x4){0.f, 0.f, 0.f, 0.f};

    for (int kc = 0; kc < 4; ++kc) {            // four K-chunks of 32
        const int kb = kc * 32;
        __syncthreads();
        #pragma unroll
        for (int p = 0; p < 4; ++p) {           // stage A (256 rows)
            int u = t + 256 * p, r = u >> 2, c = u & 3;
            size_t g = (size_t)(rowTile + r) * 128 + kb + c * 8;
            *(uint4*)&sAhi[r * ASTRIDE + c * 8] = *(const uint4*)&Xhi[g];
            *(uint4*)&sAlo[r * ASTRIDE + c * 8] = *(const uint4*)&Xlo[g];
        }
        #pragma unroll
        for (int p = 0; p < 2; ++p) {           // stage B (128 rows)
            int u = t + 256 * p, r = u >> 2, c = u & 3;
            size_t g = (size_t)(colTile + r) * 128 + kb + c * 8;
            *(uint4*)&sBhi[r * ASTRIDE + c * 8] = *(const uint4*)&Xhi[g];
            *(uint4*)&sBlo[r * ASTRIDE + c * 8] = *(const uint4*)&Xlo[g];
        }
        __syncthreads();

        short8 a[8], b[4];
        // pass 1: hi . hi
        #pragma unroll
        for (int i = 0; i < 8; ++i)
            a[i] = *(const short8*)&sAhi[(wr * 128 + 16 * i + lrow) * ASTRIDE + lkg * 8];
        #pragma unroll
        for (int j = 0; j < 4; ++j)
            b[j] = *(const short8*)&sBhi[(wc * 64 + 16 * j + lrow) * ASTRIDE + lkg * 8];
        #pragma unroll
        for (int i = 0; i < 8; ++i)
            #pragma unroll
            for (int j = 0; j < 4; ++j)
                acc[i][j] = __builtin_amdgcn_mfma_f32_16x16x32_bf16(a[i], b[j], acc[i][j], 0, 0, 0);
        // pass 2: hi . lo
        #pragma unroll
        for (int j = 0; j < 4; ++j)
            b[j] = *(const short8*)&sBlo[(wc * 64 + 16 * j + lrow) * ASTRIDE + lkg * 8];
        #pragma unroll
        for (int i = 0; i < 8; ++i)
            #pragma unroll
            for (int j = 0; j < 4; ++j)
                acc[i][j] = __builtin_amdgcn_mfma_f32_16x16x32_bf16(a[i], b[j], acc[i][j], 0, 0, 0);
        // pass 3: lo . hi
        #pragma unroll
        for (int i = 0; i < 8; ++i)
            a[i] = *(const short8*)&sAlo[(wr * 128 + 16 * i + lrow) * ASTRIDE + lkg * 8];
        #pragma unroll
        for (int j = 0; j < 4; ++j)
            b[j] = *(const short8*)&sBhi[(wc * 64 + 16 * j + lrow) * ASTRIDE + lkg * 8];
        #pragma unroll
        for (int i = 0; i < 8; ++i)
            #pragma unroll
            for (int j = 0; j < 4; ++j)
                acc[i][j] = __builtin_amdgcn_mfma_f32_16x16x32_bf16(a[i], b[j], acc[i][j], 0, 0, 0);
    }

    // ---- epilogue: collect survivors into LDS list, then flush ----
    __syncthreads();                            // all waves done reading LDS tiles
    unsigned long long* slist = (unsigned long long*)sAhi;   // 2560 u64 slots
    if (t == 0) lc = 0;
    __syncthreads();

    // C/D layout col=lane&15, row=(lane>>4)*4+reg  [m89/m91]
    float sqb[4], Tb[4]; int gcol[4];
    #pragma unroll
    for (int j = 0; j < 4; ++j) {
        gcol[j] = colTile + wc * 64 + 16 * j + lrow;
        sqb[j]  = sqn[gcol[j]];
        Tb[j]   = Tthr[gcol[j]];
    }
    #pragma unroll
    for (int i = 0; i < 8; ++i) {
        int gr0 = rowTile + wr * 128 + 16 * i + lkg * 4;
        #pragma unroll
        for (int q = 0; q < 4; ++q) {
            int gi = gr0 + q;
            float sa = sqn[gi];
            float Ti = Tthr[gi];
            #pragma unroll
            for (int j = 0; j < 4; ++j) {
                float d = fmaxf(fmaf(-2.f, acc[i][j][q], sa + sqb[j]), 0.f);
                int gj = gcol[j];
                unsigned db = __float_as_uint(d);
                if (gj >= gi && d < Ti) {       // push (owner=gi, nbr=gj)
                    int pos = atomicAdd(&lc, 1);
                    if (pos < LCAP)
                        slist[pos] = ((unsigned long long)db << 27) |
                                     ((unsigned long long)gi << 14) |
                                     (unsigned long long)(gj + 1);
                    else {                      // rare overflow: direct (slow) path
                        int p = atomicAdd(&cnt[gi], 1);
                        if (p < capb) rowbuf[(size_t)gi * capb + p] = pack_key(d, gj);
                    }
                }
                if (gj > gi && d < Tb[j]) {     // push (owner=gj, nbr=gi)
                    int pos = atomicAdd(&lc, 1);
                    if (pos < LCAP)
                        slist[pos] = ((unsigned long long)db << 27) |
                                     ((unsigned long long)gj << 14) |
                                     (unsigned long long)(gi + 1);
                    else {
                        int p = atomicAdd(&cnt[gj], 1);
                        if (p < capb) rowbuf[(size_t)gj * capb + p] = pack_key(d, gi);
                    }
                }
            }
        }
    }
    __syncthreads();
    int nlist = min(lc, LCAP);
    for (int e = t; e < nlist; e += 256) {      // cooperative flush (~5/thread)
        unsigned long long ent = slist[e];
        unsigned gj1 = (unsigned)(ent & 16383ull);
        int gi2      = (int)((ent >> 14) & 8191ull);
        unsigned db  = (unsigned)(ent >> 27);
        int p = atomicAdd(&cnt[gi2], 1);
        if (p < capb)
            rowbuf[(size_t)gi2 * capb + p] = ((unsigned long long)db << 14) |
                                             (unsigned long long)gj1;
    }
}

// ---------------- K4: exact top-20 from survivor buffer ----------------
__global__ __launch_bounds__(64) void k_sel2(const unsigned long long* __restrict__ rowbuf,
                                             const int* __restrict__ cnt,
                                             int* __restrict__ knn_idx,
                                             float* __restrict__ density,
                                             int* __restrict__ flagged,
                                             int* __restrict__ nflag, int capb) {
    int row = blockIdx.x, t = threadIdx.x;
    int n = cnt[row];
    if (n < KNN || n > capb) {                  // model miss: exact fallback handles it
        if (t == 0) { int p = atomicAdd(nflag, 1); flagged[p] = row; }
        return;
    }
    const unsigned long long* rb = rowbuf + (size_t)row * capb;
    unsigned long long v[7];                    // 7*64 = 448 >= capb
    #pragma unroll
    for (int k = 0; k < 7; ++k) { int idx = t + 64 * k; v[k] = idx < n ? rb[idx] : ~0ull; }
    unsigned long long last = 0ull;
    float sumd = 0.f;
    for (int r = 0; r < KNN; ++r) {
        unsigned long long m = ~0ull;
        #pragma unroll
        for (int k = 0; k < 7; ++k) if (v[k] > last && v[k] < m) m = v[k];
        #pragma unroll
        for (int off = 32; off; off >>= 1) {
            unsigned long long o = __shfl_down(m, off, 64);
            if (o < m) m = o;
        }
        m = __shfl(m, 0, 64);
        last = m;
        if (t == 0) {
            int j = (int)(m & 16383ull) - 1;
            if (j < 0) j = 0; if (j >= N) j = N - 1;
            knn_idx[(size_t)row * KNN + r] = j;
            sumd += sqrtf(__uint_as_float((unsigned)(m >> 14)));
        }
    }
    if (t == 0) density[row] = 1.f / (sumd * (1.f / KNN) + EPS);
}

// ---------------- K4b: exact fp32 brute-force fallback for flagged rows -------
__global__ __launch_bounds__(256) void k_fallback(const float* __restrict__ X,
                                                  const float* __restrict__ sq,
                                                  const int* __restrict__ nflag,
                                                  const int* __restrict__ flagged,
                                                  int* __restrict__ knn_idx,
                                                  float* __restrict__ density) {
    __shared__ float xr[D];
    __shared__ unsigned long long red[256];
    int t = threadIdx.x;
    int nf = *nflag;
    for (int f = blockIdx.x; f < nf; f += gridDim.x) {
        int row = flagged[f];
        __syncthreads();
        if (t < D) xr[t] = X[(size_t)row * D + t];
        __syncthreads();
        float sqr = sq[row];
        unsigned long long keys[32];
        for (int i = 0; i < 32; ++i) {
            int col = t + 256 * i;
            const float4* cp = (const float4*)(X + (size_t)col * D);
            float dot = 0.f;
            #pragma unroll
            for (int d4 = 0; d4 < 32; ++d4) {
                float4 c = cp[d4];
                float4 x = *(const float4*)&xr[d4 * 4];
                dot = fmaf(c.x, x.x, dot); dot = fmaf(c.y, x.y, dot);
                dot = fmaf(c.z, x.z, dot); dot = fmaf(c.w, x.w, dot);
            }
            float d2 = fmaxf(sqr + sq[col] - 2.f * dot, 0.f);
            keys[i] = pack_key(d2, col);
        }
        unsigned long long last = 0ull;
        float sumd = 0.f;
        for (int r = 0; r < KNN; ++r) {
            unsigned long long m = ~0ull;
            #pragma unroll
            for (int i = 0; i < 32; ++i) if (keys[i] > last && keys[i] < m) m = keys[i];
            red[t] = m; __syncthreads();
            for (int s = 128; s; s >>= 1) {
                if (t < s && red[t + s] < red[t]) red[t] = red[t + s];
                __syncthreads();
            }
            m = red[0]; __syncthreads();
            last = m;
            if (t == 0) {
                int j = (int)(m & 16383ull) - 1;
                if (j < 0) j = 0; if (j >= N) j = N - 1;
                knn_idx[(size_t)row * KNN + r] = j;
                sumd += sqrtf(__uint_as_float((unsigned)(m >> 14)));
            }
        }
        if (t == 0) density[row] = 1.f / (sumd * (1.f / KNN) + EPS);
    }
}

// ---------------- K5: scatter knn + rnn (deduped) contributions ----------------
__global__ void k_scatter(const int* __restrict__ knn_idx, const float* __restrict__ density,
                          float* __restrict__ numer, float* __restrict__ cntb) {
    int p = blockIdx.x * 256 + threadIdx.x;
    if (p >= N * KNN) return;
    int i = p / KNN;
    int j = knn_idx[p];
    atomicAdd(&numer[i], density[j]);
    atomicAdd(&cntb[i], 1.f);
    bool found = false;
    const int* kj = knn_idx + (size_t)j * KNN;
    #pragma unroll
    for (int m = 0; m < KNN; ++m) found |= (kj[m] == i);
    if (!found) {
        atomicAdd(&numer[j], density[i]);
        atomicAdd(&cntb[j], 1.f);
    }
}

// ---------------- K6: scores, flags, class preds ----------------
__global__ void k_final(const float* __restrict__ density, const float* __restrict__ numer,
                        const float* __restrict__ cntb, const float* __restrict__ logits,
                        float* __restrict__ out) {
    int i = blockIdx.x * 256 + threadIdx.x;
    if (i >= N) return;
    float c     = fmaxf(cntb[i], 1.f);
    float avg   = numer[i] / c;
    float score = -(density[i] / (avg + EPS));
    out[i] = score;
    bool flag = score < -0.5f;
    out[N + i] = flag ? 1.f : 0.f;
    const float* lg = logits + (size_t)i * NC;
    float best = lg[0]; int bi = 0;
    #pragma unroll
    for (int k = 1; k < NC; ++k) { float x = lg[k]; if (x > best) { best = x; bi = k; } }
    out[2 * N + i] = flag ? -1.f : (float)bi;
}

extern "C" void kernel_launch(void* const* d_in, const int* in_sizes, int n_in,
                              void* d_out, int out_size, void* d_ws, size_t ws_size,
                              hipStream_t stream) {
    const float* X      = (const float*)d_in[0];
    const float* logits = (const float*)d_in[1];
    float* out = (float*)d_out;

    char* w = (char*)d_ws;
    auto alloc = [&](size_t bytes) { char* p = w; w += (bytes + 255) & ~(size_t)255; return p; };
    float* sq      = (float*)alloc((size_t)N * 4);
    float* density = (float*)alloc((size_t)N * 4);
    float* numer   = (float*)alloc((size_t)N * 4);
    float* cntb    = (float*)alloc((size_t)N * 4);
    int*   knn     = (int*)alloc((size_t)N * KNN * 4);
    unsigned short* Xhi = (unsigned short*)alloc((size_t)N * D * 2);
    unsigned short* Xlo = (unsigned short*)alloc((size_t)N * D * 2);
    float* Tthr    = (float*)alloc((size_t)N * 4);
    float* m1      = (float*)alloc((size_t)(D + 2) * 4);   // col sums + {sum sq, sum sq^2}
    int*   cnt     = (int*)alloc((size_t)N * 4);
    int*   flagged = (int*)alloc((size_t)N * 4);
    int*   nflag   = (int*)alloc(256);

    // survivor buffer: sized from the ACTUAL remaining workspace (never OOB).
    unsigned long long* rowbuf = (unsigned long long*)w;
    size_t used  = (size_t)(w - (char*)d_ws);
    size_t avail = ws_size > used ? ws_size - used : 0;
    int capb = (int)(avail / ((size_t)N * 8));
    if (capb > CAPB) capb = CAPB;               // k_sel2 register budget (7*64)
    if (capb < 1) capb = 1;                     // degenerate: all rows -> exact fallback

    hipMemsetAsync(numer, 0, (size_t)N * 4, stream);
    hipMemsetAsync(cntb,  0, (size_t)N * 4, stream);
    hipMemsetAsync(m1,    0, (size_t)(D + 2) * 4, stream);
    hipMemsetAsync(cnt,   0, (size_t)N * 4, stream);
    hipMemsetAsync(nflag, 0, 4, stream);

    k_sqnorm <<<N, 64, 0, stream>>>(X, sq);
    k_split  <<<(N * D / 4 + 255) / 256, 256, 0, stream>>>(X, Xhi, Xlo);
    k_moments<<<128, 128, 0, stream>>>(X, sq, m1, m1 + D);
    k_thresh <<<N, 64, 0, stream>>>(X, sq, m1, m1 + D, Tthr);

    k_distf  <<<dim3(64, 32), 256, 0, stream>>>(Xhi, Xlo, sq, Tthr, cnt, rowbuf, capb);

    k_sel2    <<<N, 64, 0, stream>>>(rowbuf, cnt, knn, density, flagged, nflag, capb);
    k_fallback<<<64, 256, 0, stream>>>(X, sq, nflag, flagged, knn, density);

    k_scatter<<<(N * KNN + 255) / 256, 256, 0, stream>>>(knn, density, numer, cntb);
    k_final  <<<(N + 255) / 256, 256, 0, stream>>>(density, numer, cntb, logits, out);
}

// Round 4
// 321.352 us; speedup vs baseline: 1.9126x; 1.2904x over previous
//
#include <hip/hip_runtime.h>
#include <cstdint>
#include <cstddef>

#define N 8192
#define D 128
#define KNN 20
#define NC 10
#define CAPB 448          // max survivor entries per row (k_sel2 register budget: 7*64)
#define FCAP 1024         // LDS survivor-list slots in k_filter (8 KB)
#define ZTH 2.1f          // threshold z-score (expected ~146 survivors/row)
constexpr float EPS = 1e-10f;

typedef __attribute__((ext_vector_type(8))) short short8;
typedef __attribute__((ext_vector_type(4))) float f32x4;

// bf16 round-to-nearest-even, pure bit ops
__device__ inline unsigned short f32_to_bf16_rne(float x) {
    unsigned u = __float_as_uint(x);
    unsigned r = u + 0x7FFFu + ((u >> 16) & 1u);
    return (unsigned short)(r >> 16);
}
__device__ inline float bf16_to_f32(unsigned short h) {
    return __uint_as_float((unsigned)h << 16);
}
__device__ inline unsigned long long pack_key(float d, int j) {
    return ((unsigned long long)__float_as_uint(d) << 14) | (unsigned long long)(j + 1);
}

// ---------------- K1: squared norms (exact fp32) ----------------
__global__ void k_sqnorm(const float* __restrict__ X, float* __restrict__ sq) {
    int row = blockIdx.x;
    int lane = threadIdx.x;
    const float2* X2 = (const float2*)(X + (size_t)row * D);
    float2 a = X2[lane];
    float s = a.x * a.x + a.y * a.y;
    #pragma unroll
    for (int off = 32; off; off >>= 1) s += __shfl_down(s, off, 64);
    if (lane == 0) sq[row] = s;
}

// ---------------- K2: split X into bf16 hi + lo ----------------
__global__ void k_split(const float* __restrict__ X, unsigned short* __restrict__ Xhi,
                        unsigned short* __restrict__ Xlo) {
    int i = blockIdx.x * 256 + threadIdx.x;     // 1M elems / 4
    const float4* X4 = (const float4*)X;
    float4 x = X4[i];
    unsigned short h[4], l[4];
    float xs[4] = {x.x, x.y, x.z, x.w};
    #pragma unroll
    for (int q = 0; q < 4; ++q) {
        h[q] = f32_to_bf16_rne(xs[q]);
        float hf = bf16_to_f32(h[q]);
        l[q] = f32_to_bf16_rne(xs[q] - hf);
    }
    *(ushort4*)&Xhi[(size_t)i * 4] = make_ushort4(h[0], h[1], h[2], h[3]);
    *(ushort4*)&Xlo[(size_t)i * 4] = make_ushort4(l[0], l[1], l[2], l[3]);
}

// ---------------- K2b: data moments (col sums, sum sq, sum sq^2) ----------------
__global__ __launch_bounds__(128) void k_moments(const float* __restrict__ X,
                                                 const float* __restrict__ sq,
                                                 float* __restrict__ m1,
                                                 float* __restrict__ msc) {
    int b = blockIdx.x, t = threadIdx.x;        // 128 blocks x 128 threads, 64 rows each
    int r0 = b * 64;
    float s1 = 0.f;
    for (int r = 0; r < 64; ++r) s1 += X[(size_t)(r0 + r) * D + t];
    atomicAdd(&m1[t], s1);
    if (t < 64) {                               // wave 0
        float s = sq[r0 + t];
        float ss1 = s, ss2 = s * s;
        #pragma unroll
        for (int off = 32; off; off >>= 1) {
            ss1 += __shfl_down(ss1, off, 64);
            ss2 += __shfl_down(ss2, off, 64);
        }
        if (t == 0) { atomicAdd(&msc[0], ss1); atomicAdd(&msc[1], ss2); }
    }
}

// ---------------- K2c: per-row analytic survivor threshold ----------------
// mu_i = sq_i + E[sq] - 2 x_i . mean(x);  var_i = Var[sq] + 4 sq_i
__global__ void k_thresh(const float* __restrict__ X, const float* __restrict__ sq,
                         const float* __restrict__ m1, const float* __restrict__ msc,
                         float* __restrict__ T) {
    int row = blockIdx.x, lane = threadIdx.x;   // 64 lanes
    const float2* X2 = (const float2*)(X + (size_t)row * D);
    const float2* M2 = (const float2*)m1;
    float2 a = X2[lane], m = M2[lane];
    float dotp = a.x * m.x + a.y * m.y;
    #pragma unroll
    for (int off = 32; off; off >>= 1) dotp += __shfl_down(dotp, off, 64);
    if (lane == 0) {
        const float invN = 1.f / N;
        float Esq   = msc[0] * invN;
        float Esq2  = msc[1] * invN;
        float varSq = fmaxf(Esq2 - Esq * Esq, 0.f);
        float s  = sq[row];
        float mu = s + Esq - 2.f * dotp * invN;
        float var = varSq + 4.f * s;
        T[row] = mu - ZTH * sqrtf(var);
    }
}

// ---------------- K3: MFMA split-bf16 distance tile (R0-proven, verbatim) ----
// d2 = sq_i + sq_j - 2*(hi.hi + hi.lo + lo.hi); banded output.
#define ASTRIDE 40   // bf16 elems per LDS row (32 data + 8 pad); 80 B, 16B-aligned
__global__ __launch_bounds__(256) void k_distm(
        const unsigned short* __restrict__ Xhi, const unsigned short* __restrict__ Xlo,
        const float* __restrict__ sqn, float* __restrict__ d2, int R0) {
    __shared__ unsigned short sAhi[256 * ASTRIDE];
    __shared__ unsigned short sAlo[256 * ASTRIDE];
    __shared__ unsigned short sBhi[128 * ASTRIDE];
    __shared__ unsigned short sBlo[128 * ASTRIDE];

    const int t    = threadIdx.x;
    const int lane = t & 63;
    const int w    = t >> 6;
    const int wr   = w >> 1;          // 0..1 : 128-row half
    const int wc   = w & 1;           // 0..1 : 64-col half
    const int lrow = lane & 15;       // fragment row within 16
    const int lkg  = lane >> 4;       // 0..3 : k-group (8 bf16 each)

    const int rowTile = R0 + blockIdx.y * 256;
    const int colTile = blockIdx.x * 128;

    f32x4 acc[8][4];
    #pragma unroll
    for (int i = 0; i < 8; ++i)
        #pragma unroll
        for (int j = 0; j < 4; ++j) acc[i][j] = (f32x4){0.f, 0.f, 0.f, 0.f};

    for (int kc = 0; kc < 4; ++kc) {            // four K-chunks of 32
        const int kb = kc * 32;
        __syncthreads();
        #pragma unroll
        for (int p = 0; p < 4; ++p) {           // stage A (256 rows)
            int u = t + 256 * p, r = u >> 2, c = u & 3;
            size_t g = (size_t)(rowTile + r) * 128 + kb + c * 8;
            *(uint4*)&sAhi[r * ASTRIDE + c * 8] = *(const uint4*)&Xhi[g];
            *(uint4*)&sAlo[r * ASTRIDE + c * 8] = *(const uint4*)&Xlo[g];
        }
        #pragma unroll
        for (int p = 0; p < 2; ++p) {           // stage B (128 rows)
            int u = t + 256 * p, r = u >> 2, c = u & 3;
            size_t g = (size_t)(colTile + r) * 128 + kb + c * 8;
            *(uint4*)&sBhi[r * ASTRIDE + c * 8] = *(const uint4*)&Xhi[g];
            *(uint4*)&sBlo[r * ASTRIDE + c * 8] = *(const uint4*)&Xlo[g];
        }
        __syncthreads();

        short8 a[8], b[4];
        // pass 1: hi . hi
        #pragma unroll
        for (int i = 0; i < 8; ++i)
            a[i] = *(const short8*)&sAhi[(wr * 128 + 16 * i + lrow) * ASTRIDE + lkg * 8];
        #pragma unroll
        for (int j = 0; j < 4; ++j)
            b[j] = *(const short8*)&sBhi[(wc * 64 + 16 * j + lrow) * ASTRIDE + lkg * 8];
        #pragma unroll
        for (int i = 0; i < 8; ++i)
            #pragma unroll
            for (int j = 0; j < 4; ++j)
                acc[i][j] = __builtin_amdgcn_mfma_f32_16x16x32_bf16(a[i], b[j], acc[i][j], 0, 0, 0);
        // pass 2: hi . lo   (reload b only)
        #pragma unroll
        for (int j = 0; j < 4; ++j)
            b[j] = *(const short8*)&sBlo[(wc * 64 + 16 * j + lrow) * ASTRIDE + lkg * 8];
        #pragma unroll
        for (int i = 0; i < 8; ++i)
            #pragma unroll
            for (int j = 0; j < 4; ++j)
                acc[i][j] = __builtin_amdgcn_mfma_f32_16x16x32_bf16(a[i], b[j], acc[i][j], 0, 0, 0);
        // pass 3: lo . hi   (reload both)
        #pragma unroll
        for (int i = 0; i < 8; ++i)
            a[i] = *(const short8*)&sAlo[(wr * 128 + 16 * i + lrow) * ASTRIDE + lkg * 8];
        #pragma unroll
        for (int j = 0; j < 4; ++j)
            b[j] = *(const short8*)&sBhi[(wc * 64 + 16 * j + lrow) * ASTRIDE + lkg * 8];
        #pragma unroll
        for (int i = 0; i < 8; ++i)
            #pragma unroll
            for (int j = 0; j < 4; ++j)
                acc[i][j] = __builtin_amdgcn_mfma_f32_16x16x32_bf16(a[i], b[j], acc[i][j], 0, 0, 0);
    }

    // epilogue: C/D layout col=lane&15, row=(lane>>4)*4+reg  [m89/m91]
    float sqb[4];
    #pragma unroll
    for (int j = 0; j < 4; ++j)
        sqb[j] = sqn[colTile + wc * 64 + 16 * j + lrow];
    #pragma unroll
    for (int i = 0; i < 8; ++i) {
        int lr0 = blockIdx.y * 256 + wr * 128 + 16 * i + lkg * 4;   // band-local row (reg 0)
        #pragma unroll
        for (int q = 0; q < 4; ++q) {
            float sa = sqn[R0 + lr0 + q];
            #pragma unroll
            for (int j = 0; j < 4; ++j) {
                float d = fmaxf(fmaf(-2.f, acc[i][j][q], sa + sqb[j]), 0.f);
                d2[(size_t)(lr0 + q) * N + colTile + wc * 64 + 16 * j + lrow] = d;
            }
        }
    }
}

// ---------------- K3b: stream d2 row, keep survivors (no global atomics) ------
// One block per band-row; each row is owned by exactly one block across the
// whole run, so cnt[row] is a plain store and rowbuf writes are coalesced.
__global__ __launch_bounds__(256) void k_filter(const float* __restrict__ d2, int R0,
                                                const float* __restrict__ Tthr,
                                                int* __restrict__ cnt,
                                                unsigned long long* __restrict__ rowbuf,
                                                int capb) {
    __shared__ unsigned long long sl[FCAP];
    __shared__ int lc;
    int lrow = blockIdx.x;
    int row  = R0 + lrow;
    int t    = threadIdx.x;
    float T  = Tthr[row];
    if (t == 0) lc = 0;
    __syncthreads();
    const float4* rp = (const float4*)(d2 + (size_t)lrow * N);
    #pragma unroll
    for (int p = 0; p < 8; ++p) {
        float4 g = rp[t + 256 * p];
        float vs[4] = {g.x, g.y, g.z, g.w};
        #pragma unroll
        for (int q = 0; q < 4; ++q) {
            if (vs[q] < T) {
                int pos = atomicAdd(&lc, 1);
                if (pos < FCAP) sl[pos] = pack_key(vs[q], 4 * (t + 256 * p) + q);
            }
        }
    }
    __syncthreads();
    int m = lc;
    if (t == 0) cnt[row] = (m > FCAP) ? capb + 1 : m;   // LDS overflow -> force fallback
    int mm = min(m, min(capb, FCAP));
    for (int e = t; e < mm; e += 256)
        rowbuf[(size_t)row * capb + e] = sl[e];
}

// ---------------- K4: exact top-20 from survivor buffer ----------------
__global__ __launch_bounds__(64) void k_sel2(const unsigned long long* __restrict__ rowbuf,
                                             const int* __restrict__ cnt,
                                             int* __restrict__ knn_idx,
                                             float* __restrict__ density,
                                             int* __restrict__ flagged,
                                             int* __restrict__ nflag, int capb) {
    int row = blockIdx.x, t = threadIdx.x;
    int n = cnt[row];
    if (n < KNN || n > capb) {                  // model miss: exact fallback handles it
        if (t == 0) { int p = atomicAdd(nflag, 1); flagged[p] = row; }
        return;
    }
    const unsigned long long* rb = rowbuf + (size_t)row * capb;
    unsigned long long v[7];                    // 7*64 = 448 >= capb
    #pragma unroll
    for (int k = 0; k < 7; ++k) { int idx = t + 64 * k; v[k] = idx < n ? rb[idx] : ~0ull; }
    unsigned long long last = 0ull;
    float sumd = 0.f;
    for (int r = 0; r < KNN; ++r) {
        unsigned long long m = ~0ull;
        #pragma unroll
        for (int k = 0; k < 7; ++k) if (v[k] > last && v[k] < m) m = v[k];
        #pragma unroll
        for (int off = 32; off; off >>= 1) {
            unsigned long long o = __shfl_down(m, off, 64);
            if (o < m) m = o;
        }
        m = __shfl(m, 0, 64);
        last = m;
        if (t == 0) {
            int j = (int)(m & 16383ull) - 1;
            if (j < 0) j = 0; if (j >= N) j = N - 1;
            knn_idx[(size_t)row * KNN + r] = j;
            sumd += sqrtf(__uint_as_float((unsigned)(m >> 14)));
        }
    }
    if (t == 0) density[row] = 1.f / (sumd * (1.f / KNN) + EPS);
}

// ---------------- K4b: exact fp32 brute-force fallback for flagged rows -------
__global__ __launch_bounds__(256) void k_fallback(const float* __restrict__ X,
                                                  const float* __restrict__ sq,
                                                  const int* __restrict__ nflag,
                                                  const int* __restrict__ flagged,
                                                  int* __restrict__ knn_idx,
                                                  float* __restrict__ density) {
    __shared__ float xr[D];
    __shared__ unsigned long long red[256];
    int t = threadIdx.x;
    int nf = *nflag;
    for (int f = blockIdx.x; f < nf; f += gridDim.x) {
        int row = flagged[f];
        __syncthreads();
        if (t < D) xr[t] = X[(size_t)row * D + t];
        __syncthreads();
        float sqr = sq[row];
        unsigned long long keys[32];
        for (int i = 0; i < 32; ++i) {
            int col = t + 256 * i;
            const float4* cp = (const float4*)(X + (size_t)col * D);
            float dot = 0.f;
            #pragma unroll
            for (int d4 = 0; d4 < 32; ++d4) {
                float4 c = cp[d4];
                float4 x = *(const float4*)&xr[d4 * 4];
                dot = fmaf(c.x, x.x, dot); dot = fmaf(c.y, x.y, dot);
                dot = fmaf(c.z, x.z, dot); dot = fmaf(c.w, x.w, dot);
            }
            float d2v = fmaxf(sqr + sq[col] - 2.f * dot, 0.f);
            keys[i] = pack_key(d2v, col);
        }
        unsigned long long last = 0ull;
        float sumd = 0.f;
        for (int r = 0; r < KNN; ++r) {
            unsigned long long m = ~0ull;
            #pragma unroll
            for (int i = 0; i < 32; ++i) if (keys[i] > last && keys[i] < m) m = keys[i];
            red[t] = m; __syncthreads();
            for (int s = 128; s; s >>= 1) {
                if (t < s && red[t + s] < red[t]) red[t] = red[t + s];
                __syncthreads();
            }
            m = red[0]; __syncthreads();
            last = m;
            if (t == 0) {
                int j = (int)(m & 16383ull) - 1;
                if (j < 0) j = 0; if (j >= N) j = N - 1;
                knn_idx[(size_t)row * KNN + r] = j;
                sumd += sqrtf(__uint_as_float((unsigned)(m >> 14)));
            }
        }
        if (t == 0) density[row] = 1.f / (sumd * (1.f / KNN) + EPS);
    }
}

// ---------------- K5: scatter knn + rnn (deduped) contributions ----------------
__global__ void k_scatter(const int* __restrict__ knn_idx, const float* __restrict__ density,
                          float* __restrict__ numer, float* __restrict__ cntb) {
    int p = blockIdx.x * 256 + threadIdx.x;
    if (p >= N * KNN) return;
    int i = p / KNN;
    int j = knn_idx[p];
    atomicAdd(&numer[i], density[j]);
    atomicAdd(&cntb[i], 1.f);
    bool found = false;
    const int* kj = knn_idx + (size_t)j * KNN;
    #pragma unroll
    for (int m = 0; m < KNN; ++m) found |= (kj[m] == i);
    if (!found) {
        atomicAdd(&numer[j], density[i]);
        atomicAdd(&cntb[j], 1.f);
    }
}

// ---------------- K6: scores, flags, class preds ----------------
__global__ void k_final(const float* __restrict__ density, const float* __restrict__ numer,
                        const float* __restrict__ cntb, const float* __restrict__ logits,
                        float* __restrict__ out) {
    int i = blockIdx.x * 256 + threadIdx.x;
    if (i >= N) return;
    float c     = fmaxf(cntb[i], 1.f);
    float avg   = numer[i] / c;
    float score = -(density[i] / (avg + EPS));
    out[i] = score;
    bool flag = score < -0.5f;
    out[N + i] = flag ? 1.f : 0.f;
    const float* lg = logits + (size_t)i * NC;
    float best = lg[0]; int bi = 0;
    #pragma unroll
    for (int k = 1; k < NC; ++k) { float x = lg[k]; if (x > best) { best = x; bi = k; } }
    out[2 * N + i] = flag ? -1.f : (float)bi;
}

extern "C" void kernel_launch(void* const* d_in, const int* in_sizes, int n_in,
                              void* d_out, int out_size, void* d_ws, size_t ws_size,
                              hipStream_t stream) {
    const float* X      = (const float*)d_in[0];
    const float* logits = (const float*)d_in[1];
    float* out = (float*)d_out;

    char* w = (char*)d_ws;
    auto alloc = [&](size_t bytes) { char* p = w; w += (bytes + 255) & ~(size_t)255; return p; };
    float* sq      = (float*)alloc((size_t)N * 4);
    float* density = (float*)alloc((size_t)N * 4);
    float* numer   = (float*)alloc((size_t)N * 4);
    float* cntb    = (float*)alloc((size_t)N * 4);
    int*   knn     = (int*)alloc((size_t)N * KNN * 4);
    unsigned short* Xhi = (unsigned short*)alloc((size_t)N * D * 2);
    unsigned short* Xlo = (unsigned short*)alloc((size_t)N * D * 2);
    float* Tthr    = (float*)alloc((size_t)N * 4);
    float* m1      = (float*)alloc((size_t)(D + 2) * 4);
    int*   cnt     = (int*)alloc((size_t)N * 4);
    int*   flagged = (int*)alloc((size_t)N * 4);
    int*   nflag   = (int*)alloc(256);

    size_t used  = (size_t)(w - (char*)d_ws);
    size_t avail = ws_size > used ? ws_size - used : 0;

    // pick (band, capb) to fit: rowbuf N*capb*8 + d2band band*N*4
    int capb = CAPB;
    int band = 2048;
    while (band > 256 && (size_t)band * N * 4 + (size_t)N * capb * 8 > avail) band >>= 1;
    if ((size_t)band * N * 4 + (size_t)N * capb * 8 > avail) {
        size_t left = avail > (size_t)band * N * 4 ? avail - (size_t)band * N * 4 : 0;
        capb = (int)(left / ((size_t)N * 8));
        if (capb > CAPB) capb = CAPB;
        if (capb < 1) capb = 1;                 // degenerate: all rows -> exact fallback
    }
    unsigned long long* rowbuf = (unsigned long long*)alloc((size_t)N * capb * 8);
    float* d2band = (float*)w;                  // band*N*4 (L3-resident at band=2048)

    hipMemsetAsync(numer, 0, (size_t)N * 4, stream);
    hipMemsetAsync(cntb,  0, (size_t)N * 4, stream);
    hipMemsetAsync(m1,    0, (size_t)(D + 2) * 4, stream);
    hipMemsetAsync(nflag, 0, 4, stream);

    k_sqnorm <<<N, 64, 0, stream>>>(X, sq);
    k_split  <<<(N * D / 4 + 255) / 256, 256, 0, stream>>>(X, Xhi, Xlo);
    k_moments<<<128, 128, 0, stream>>>(X, sq, m1, m1 + D);
    k_thresh <<<N, 64, 0, stream>>>(X, sq, m1, m1 + D, Tthr);

    for (int R0 = 0; R0 < N; R0 += band) {
        int rows = min(band, N - R0);
        dim3 g(N / 128, rows / 256);
        k_distm <<<g, 256, 0, stream>>>(Xhi, Xlo, sq, d2band, R0);
        k_filter<<<rows, 256, 0, stream>>>(d2band, R0, Tthr, cnt, rowbuf, capb);
    }

    k_sel2    <<<N, 64, 0, stream>>>(rowbuf, cnt, knn, density, flagged, nflag, capb);
    k_fallback<<<64, 256, 0, stream>>>(X, sq, nflag, flagged, knn, density);

    k_scatter<<<(N * KNN + 255) / 256, 256, 0, stream>>>(knn, density, numer, cntb);
    k_final  <<<(N + 255) / 256, 256, 0, stream>>>(density, numer, cntb, logits, out);
}

// Round 5
// 274.943 us; speedup vs baseline: 2.2355x; 1.1688x over previous
//
#include <hip/hip_runtime.h>
#include <cstdint>
#include <cstddef>

#define N 8192
#define D 128
#define KNN 20
#define NC 10
#define CAPB 448          // max survivor entries per row (k_sel2 register budget: 7*64)
#define FCAP 1024         // LDS survivor-list slots in k_filter (8 KB)
#define ZTH 2.1f          // threshold z-score (expected ~146 survivors/row)
#define NW (N / 32)       // bitmap words per row
constexpr float EPS = 1e-10f;

typedef __attribute__((ext_vector_type(8))) short short8;
typedef __attribute__((ext_vector_type(4))) float f32x4;

// bf16 round-to-nearest-even, pure bit ops
__device__ inline unsigned short f32_to_bf16_rne(float x) {
    unsigned u = __float_as_uint(x);
    unsigned r = u + 0x7FFFu + ((u >> 16) & 1u);
    return (unsigned short)(r >> 16);
}
__device__ inline float bf16_to_f32(unsigned short h) {
    return __uint_as_float((unsigned)h << 16);
}
__device__ inline unsigned long long pack_key(float d, int j) {
    return ((unsigned long long)__float_as_uint(d) << 14) | (unsigned long long)(j + 1);
}

// ---------------- K1: squared norms (exact fp32) ----------------
__global__ void k_sqnorm(const float* __restrict__ X, float* __restrict__ sq) {
    int row = blockIdx.x;
    int lane = threadIdx.x;
    const float2* X2 = (const float2*)(X + (size_t)row * D);
    float2 a = X2[lane];
    float s = a.x * a.x + a.y * a.y;
    #pragma unroll
    for (int off = 32; off; off >>= 1) s += __shfl_down(s, off, 64);
    if (lane == 0) sq[row] = s;
}

// ---------------- K2: split X into bf16 hi + lo ----------------
__global__ void k_split(const float* __restrict__ X, unsigned short* __restrict__ Xhi,
                        unsigned short* __restrict__ Xlo) {
    int i = blockIdx.x * 256 + threadIdx.x;     // 1M elems / 4
    const float4* X4 = (const float4*)X;
    float4 x = X4[i];
    unsigned short h[4], l[4];
    float xs[4] = {x.x, x.y, x.z, x.w};
    #pragma unroll
    for (int q = 0; q < 4; ++q) {
        h[q] = f32_to_bf16_rne(xs[q]);
        float hf = bf16_to_f32(h[q]);
        l[q] = f32_to_bf16_rne(xs[q] - hf);
    }
    *(ushort4*)&Xhi[(size_t)i * 4] = make_ushort4(h[0], h[1], h[2], h[3]);
    *(ushort4*)&Xlo[(size_t)i * 4] = make_ushort4(l[0], l[1], l[2], l[3]);
}

// ---------------- K2b: data moments (col sums, sum sq, sum sq^2) ----------------
__global__ __launch_bounds__(128) void k_moments(const float* __restrict__ X,
                                                 const float* __restrict__ sq,
                                                 float* __restrict__ m1,
                                                 float* __restrict__ msc) {
    int b = blockIdx.x, t = threadIdx.x;        // 128 blocks x 128 threads, 64 rows each
    int r0 = b * 64;
    float s1 = 0.f;
    for (int r = 0; r < 64; ++r) s1 += X[(size_t)(r0 + r) * D + t];
    atomicAdd(&m1[t], s1);
    if (t < 64) {                               // wave 0
        float s = sq[r0 + t];
        float ss1 = s, ss2 = s * s;
        #pragma unroll
        for (int off = 32; off; off >>= 1) {
            ss1 += __shfl_down(ss1, off, 64);
            ss2 += __shfl_down(ss2, off, 64);
        }
        if (t == 0) { atomicAdd(&msc[0], ss1); atomicAdd(&msc[1], ss2); }
    }
}

// ---------------- K2c: per-row analytic survivor threshold ----------------
// mu_i = sq_i + E[sq] - 2 x_i . mean(x);  var_i = Var[sq] + 4 sq_i
__global__ void k_thresh(const float* __restrict__ X, const float* __restrict__ sq,
                         const float* __restrict__ m1, const float* __restrict__ msc,
                         float* __restrict__ T) {
    int row = blockIdx.x, lane = threadIdx.x;   // 64 lanes
    const float2* X2 = (const float2*)(X + (size_t)row * D);
    const float2* M2 = (const float2*)m1;
    float2 a = X2[lane], m = M2[lane];
    float dotp = a.x * m.x + a.y * m.y;
    #pragma unroll
    for (int off = 32; off; off >>= 1) dotp += __shfl_down(dotp, off, 64);
    if (lane == 0) {
        const float invN = 1.f / N;
        float Esq   = msc[0] * invN;
        float Esq2  = msc[1] * invN;
        float varSq = fmaxf(Esq2 - Esq * Esq, 0.f);
        float s  = sq[row];
        float mu = s + Esq - 2.f * dotp * invN;
        float var = varSq + 4.f * s;
        T[row] = mu - ZTH * sqrtf(var);
    }
}

// ---------------- K3: MFMA split-bf16 distance, 128x128 tile ----------------
// Same per-element accumulation sequence as the verified 256x128 kernel
// (4 k-chunks x {hi.hi, hi.lo, lo.hi}) -> bit-identical d2. Tile halved to
// cut acc VGPRs 128->64 and LDS 61440->40960 for higher occupancy.
#define ASTRIDE 40   // bf16 elems per LDS row (32 data + 8 pad); 80 B, 16B-aligned
__global__ __launch_bounds__(256, 3) void k_distm(
        const unsigned short* __restrict__ Xhi, const unsigned short* __restrict__ Xlo,
        const float* __restrict__ sqn, float* __restrict__ d2, int R0) {
    __shared__ unsigned short sAhi[128 * ASTRIDE];
    __shared__ unsigned short sAlo[128 * ASTRIDE];
    __shared__ unsigned short sBhi[128 * ASTRIDE];
    __shared__ unsigned short sBlo[128 * ASTRIDE];

    const int t    = threadIdx.x;
    const int lane = t & 63;
    const int w    = t >> 6;
    const int wr   = w >> 1;          // 0..1 : 64-row half
    const int wc   = w & 1;           // 0..1 : 64-col half
    const int lrow = lane & 15;       // fragment row within 16
    const int lkg  = lane >> 4;       // 0..3 : k-group (8 bf16 each)

    const int rowTile = R0 + blockIdx.y * 128;
    const int colTile = blockIdx.x * 128;

    f32x4 acc[4][4];
    #pragma unroll
    for (int i = 0; i < 4; ++i)
        #pragma unroll
        for (int j = 0; j < 4; ++j) acc[i][j] = (f32x4){0.f, 0.f, 0.f, 0.f};

    for (int kc = 0; kc < 4; ++kc) {            // four K-chunks of 32
        const int kb = kc * 32;
        __syncthreads();
        #pragma unroll
        for (int p = 0; p < 2; ++p) {           // stage A (128 rows): 512 chunks/256thr
            int u = t + 256 * p, r = u >> 2, c = u & 3;
            size_t g = (size_t)(rowTile + r) * 128 + kb + c * 8;
            *(uint4*)&sAhi[r * ASTRIDE + c * 8] = *(const uint4*)&Xhi[g];
            *(uint4*)&sAlo[r * ASTRIDE + c * 8] = *(const uint4*)&Xlo[g];
        }
        #pragma unroll
        for (int p = 0; p < 2; ++p) {           // stage B (128 rows)
            int u = t + 256 * p, r = u >> 2, c = u & 3;
            size_t g = (size_t)(colTile + r) * 128 + kb + c * 8;
            *(uint4*)&sBhi[r * ASTRIDE + c * 8] = *(const uint4*)&Xhi[g];
            *(uint4*)&sBlo[r * ASTRIDE + c * 8] = *(const uint4*)&Xlo[g];
        }
        __syncthreads();

        short8 a[4], b[4];
        // pass 1: hi . hi
        #pragma unroll
        for (int i = 0; i < 4; ++i)
            a[i] = *(const short8*)&sAhi[(wr * 64 + 16 * i + lrow) * ASTRIDE + lkg * 8];
        #pragma unroll
        for (int j = 0; j < 4; ++j)
            b[j] = *(const short8*)&sBhi[(wc * 64 + 16 * j + lrow) * ASTRIDE + lkg * 8];
        #pragma unroll
        for (int i = 0; i < 4; ++i)
            #pragma unroll
            for (int j = 0; j < 4; ++j)
                acc[i][j] = __builtin_amdgcn_mfma_f32_16x16x32_bf16(a[i], b[j], acc[i][j], 0, 0, 0);
        // pass 2: hi . lo   (reload b only)
        #pragma unroll
        for (int j = 0; j < 4; ++j)
            b[j] = *(const short8*)&sBlo[(wc * 64 + 16 * j + lrow) * ASTRIDE + lkg * 8];
        #pragma unroll
        for (int i = 0; i < 4; ++i)
            #pragma unroll
            for (int j = 0; j < 4; ++j)
                acc[i][j] = __builtin_amdgcn_mfma_f32_16x16x32_bf16(a[i], b[j], acc[i][j], 0, 0, 0);
        // pass 3: lo . hi   (reload both)
        #pragma unroll
        for (int i = 0; i < 4; ++i)
            a[i] = *(const short8*)&sAlo[(wr * 64 + 16 * i + lrow) * ASTRIDE + lkg * 8];
        #pragma unroll
        for (int j = 0; j < 4; ++j)
            b[j] = *(const short8*)&sBhi[(wc * 64 + 16 * j + lrow) * ASTRIDE + lkg * 8];
        #pragma unroll
        for (int i = 0; i < 4; ++i)
            #pragma unroll
            for (int j = 0; j < 4; ++j)
                acc[i][j] = __builtin_amdgcn_mfma_f32_16x16x32_bf16(a[i], b[j], acc[i][j], 0, 0, 0);
    }

    // epilogue: C/D layout col=lane&15, row=(lane>>4)*4+reg  [m89/m91]
    float sqb[4];
    #pragma unroll
    for (int j = 0; j < 4; ++j)
        sqb[j] = sqn[colTile + wc * 64 + 16 * j + lrow];
    #pragma unroll
    for (int i = 0; i < 4; ++i) {
        int lr0 = blockIdx.y * 128 + wr * 64 + 16 * i + lkg * 4;   // band-local row (reg 0)
        #pragma unroll
        for (int q = 0; q < 4; ++q) {
            float sa = sqn[R0 + lr0 + q];
            #pragma unroll
            for (int j = 0; j < 4; ++j) {
                float d = fmaxf(fmaf(-2.f, acc[i][j][q], sa + sqb[j]), 0.f);
                d2[(size_t)(lr0 + q) * N + colTile + wc * 64 + 16 * j + lrow] = d;
            }
        }
    }
}

// ---------------- K3b: stream d2 row, keep survivors (no global atomics) ------
__global__ __launch_bounds__(256) void k_filter(const float* __restrict__ d2, int R0,
                                                const float* __restrict__ Tthr,
                                                int* __restrict__ cnt,
                                                unsigned long long* __restrict__ rowbuf,
                                                int capb) {
    __shared__ unsigned long long sl[FCAP];
    __shared__ int lc;
    int lrow = blockIdx.x;
    int row  = R0 + lrow;
    int t    = threadIdx.x;
    float T  = Tthr[row];
    if (t == 0) lc = 0;
    __syncthreads();
    const float4* rp = (const float4*)(d2 + (size_t)lrow * N);
    #pragma unroll
    for (int p = 0; p < 8; ++p) {
        float4 g = rp[t + 256 * p];
        float vs[4] = {g.x, g.y, g.z, g.w};
        #pragma unroll
        for (int q = 0; q < 4; ++q) {
            if (vs[q] < T) {
                int pos = atomicAdd(&lc, 1);
                if (pos < FCAP) sl[pos] = pack_key(vs[q], 4 * (t + 256 * p) + q);
            }
        }
    }
    __syncthreads();
    int m = lc;
    if (t == 0) cnt[row] = (m > FCAP) ? capb + 1 : m;   // LDS overflow -> force fallback
    int mm = min(m, min(capb, FCAP));
    for (int e = t; e < mm; e += 256)
        rowbuf[(size_t)row * capb + e] = sl[e];
}

// ---------------- K4: exact top-20 from survivor buffer ----------------
__global__ __launch_bounds__(64) void k_sel2(const unsigned long long* __restrict__ rowbuf,
                                             const int* __restrict__ cnt,
                                             int* __restrict__ knn_idx,
                                             float* __restrict__ density,
                                             int* __restrict__ flagged,
                                             int* __restrict__ nflag, int capb) {
    int row = blockIdx.x, t = threadIdx.x;
    int n = cnt[row];
    if (n < KNN || n > capb) {                  // model miss: exact fallback handles it
        if (t == 0) { int p = atomicAdd(nflag, 1); flagged[p] = row; }
        return;
    }
    const unsigned long long* rb = rowbuf + (size_t)row * capb;
    unsigned long long v[7];                    // 7*64 = 448 >= capb
    #pragma unroll
    for (int k = 0; k < 7; ++k) { int idx = t + 64 * k; v[k] = idx < n ? rb[idx] : ~0ull; }
    unsigned long long last = 0ull;
    float sumd = 0.f;
    for (int r = 0; r < KNN; ++r) {
        unsigned long long m = ~0ull;
        #pragma unroll
        for (int k = 0; k < 7; ++k) if (v[k] > last && v[k] < m) m = v[k];
        #pragma unroll
        for (int off = 32; off; off >>= 1) {
            unsigned long long o = __shfl_down(m, off, 64);
            if (o < m) m = o;
        }
        m = __shfl(m, 0, 64);
        last = m;
        if (t == 0) {
            int j = (int)(m & 16383ull) - 1;
            if (j < 0) j = 0; if (j >= N) j = N - 1;
            knn_idx[(size_t)row * KNN + r] = j;
            sumd += sqrtf(__uint_as_float((unsigned)(m >> 14)));
        }
    }
    if (t == 0) density[row] = 1.f / (sumd * (1.f / KNN) + EPS);
}

// ---------------- K4b: exact fp32 brute-force fallback for flagged rows -------
__global__ __launch_bounds__(256) void k_fallback(const float* __restrict__ X,
                                                  const float* __restrict__ sq,
                                                  const int* __restrict__ nflag,
                                                  const int* __restrict__ flagged,
                                                  int* __restrict__ knn_idx,
                                                  float* __restrict__ density) {
    __shared__ float xr[D];
    __shared__ unsigned long long red[256];
    int t = threadIdx.x;
    int nf = *nflag;
    for (int f = blockIdx.x; f < nf; f += gridDim.x) {
        int row = flagged[f];
        __syncthreads();
        if (t < D) xr[t] = X[(size_t)row * D + t];
        __syncthreads();
        float sqr = sq[row];
        unsigned long long keys[32];
        for (int i = 0; i < 32; ++i) {
            int col = t + 256 * i;
            const float4* cp = (const float4*)(X + (size_t)col * D);
            float dot = 0.f;
            #pragma unroll
            for (int d4 = 0; d4 < 32; ++d4) {
                float4 c = cp[d4];
                float4 x = *(const float4*)&xr[d4 * 4];
                dot = fmaf(c.x, x.x, dot); dot = fmaf(c.y, x.y, dot);
                dot = fmaf(c.z, x.z, dot); dot = fmaf(c.w, x.w, dot);
            }
            float d2v = fmaxf(sqr + sq[col] - 2.f * dot, 0.f);
            keys[i] = pack_key(d2v, col);
        }
        unsigned long long last = 0ull;
        float sumd = 0.f;
        for (int r = 0; r < KNN; ++r) {
            unsigned long long m = ~0ull;
            #pragma unroll
            for (int i = 0; i < 32; ++i) if (keys[i] > last && keys[i] < m) m = keys[i];
            red[t] = m; __syncthreads();
            for (int s = 128; s; s >>= 1) {
                if (t < s && red[t + s] < red[t]) red[t] = red[t + s];
                __syncthreads();
            }
            m = red[0]; __syncthreads();
            last = m;
            if (t == 0) {
                int j = (int)(m & 16383ull) - 1;
                if (j < 0) j = 0; if (j >= N) j = N - 1;
                knn_idx[(size_t)row * KNN + r] = j;
                sumd += sqrtf(__uint_as_float((unsigned)(m >> 14)));
            }
        }
        if (t == 0) density[row] = 1.f / (sumd * (1.f / KNN) + EPS);
    }
}

// ---------------- K5a: kNN membership bitmap (exact) ----------------
__global__ void k_setbits(const int* __restrict__ knn_idx, unsigned* __restrict__ bits) {
    int p = blockIdx.x * 256 + threadIdx.x;
    if (p >= N * KNN) return;
    int i = p / KNN;
    int j = knn_idx[p];
    atomicOr(&bits[(size_t)i * NW + (j >> 5)], 1u << (j & 31));
}

// ---------------- K5b: forward kNN sums (row-owned, zero atomics) ------------
__global__ void k_rowsum(const int* __restrict__ knn_idx, const float* __restrict__ density,
                         float* __restrict__ numer, float* __restrict__ cntb) {
    int i = blockIdx.x * 256 + threadIdx.x;
    if (i >= N) return;
    const int* ki = knn_idx + (size_t)i * KNN;
    float s = 0.f;
    #pragma unroll
    for (int m = 0; m < KNN; ++m) s += density[ki[m]];
    numer[i] = s;
    cntb[i] = (float)KNN;
}

// ---------------- K5c: reverse non-mutual contributions (bitmap test) --------
__global__ void k_rev(const int* __restrict__ knn_idx, const float* __restrict__ density,
                      const unsigned* __restrict__ bits,
                      float* __restrict__ numer, float* __restrict__ cntb) {
    int p = blockIdx.x * 256 + threadIdx.x;
    if (p >= N * KNN) return;
    int i = p / KNN;
    int j = knn_idx[p];
    unsigned wd = bits[(size_t)j * NW + (i >> 5)];
    if (!(wd & (1u << (i & 31)))) {             // i not in knn(j): non-mutual edge
        atomicAdd(&numer[j], density[i]);
        atomicAdd(&cntb[j], 1.f);
    }
}

// ---------------- K6: scores, flags, class preds ----------------
__global__ void k_final(const float* __restrict__ density, const float* __restrict__ numer,
                        const float* __restrict__ cntb, const float* __restrict__ logits,
                        float* __restrict__ out) {
    int i = blockIdx.x * 256 + threadIdx.x;
    if (i >= N) return;
    float c     = fmaxf(cntb[i], 1.f);
    float avg   = numer[i] / c;
    float score = -(density[i] / (avg + EPS));
    out[i] = score;
    bool flag = score < -0.5f;
    out[N + i] = flag ? 1.f : 0.f;
    const float* lg = logits + (size_t)i * NC;
    float best = lg[0]; int bi = 0;
    #pragma unroll
    for (int k = 1; k < NC; ++k) { float x = lg[k]; if (x > best) { best = x; bi = k; } }
    out[2 * N + i] = flag ? -1.f : (float)bi;
}

extern "C" void kernel_launch(void* const* d_in, const int* in_sizes, int n_in,
                              void* d_out, int out_size, void* d_ws, size_t ws_size,
                              hipStream_t stream) {
    const float* X      = (const float*)d_in[0];
    const float* logits = (const float*)d_in[1];
    float* out = (float*)d_out;

    char* w = (char*)d_ws;
    auto alloc = [&](size_t bytes) { char* p = w; w += (bytes + 255) & ~(size_t)255; return p; };
    float* sq      = (float*)alloc((size_t)N * 4);
    float* density = (float*)alloc((size_t)N * 4);
    float* numer   = (float*)alloc((size_t)N * 4);
    float* cntb    = (float*)alloc((size_t)N * 4);
    int*   knn     = (int*)alloc((size_t)N * KNN * 4);
    unsigned short* Xhi = (unsigned short*)alloc((size_t)N * D * 2);
    unsigned short* Xlo = (unsigned short*)alloc((size_t)N * D * 2);
    float* Tthr    = (float*)alloc((size_t)N * 4);
    float* m1      = (float*)alloc((size_t)(D + 2) * 4);
    int*   cnt     = (int*)alloc((size_t)N * 4);
    int*   flagged = (int*)alloc((size_t)N * 4);
    int*   nflag   = (int*)alloc(256);
    unsigned* bits = (unsigned*)alloc((size_t)N * NW * 4);   // 8 MB kNN bitmap

    size_t used  = (size_t)(w - (char*)d_ws);
    size_t avail = ws_size > used ? ws_size - used : 0;

    // pick (band, capb) to fit: rowbuf N*capb*8 + d2band band*N*4
    int capb = CAPB;
    int band = 2048;
    while (band > 256 && (size_t)band * N * 4 + (size_t)N * capb * 8 > avail) band >>= 1;
    if ((size_t)band * N * 4 + (size_t)N * capb * 8 > avail) {
        size_t left = avail > (size_t)band * N * 4 ? avail - (size_t)band * N * 4 : 0;
        capb = (int)(left / ((size_t)N * 8));
        if (capb > CAPB) capb = CAPB;
        if (capb < 1) capb = 1;                 // degenerate: all rows -> exact fallback
    }
    unsigned long long* rowbuf = (unsigned long long*)alloc((size_t)N * capb * 8);
    float* d2band = (float*)w;                  // band*N*4 (L3-resident at band=2048)

    hipMemsetAsync(bits,  0, (size_t)N * NW * 4, stream);
    hipMemsetAsync(m1,    0, (size_t)(D + 2) * 4, stream);
    hipMemsetAsync(nflag, 0, 4, stream);

    k_sqnorm <<<N, 64, 0, stream>>>(X, sq);
    k_split  <<<(N * D / 4 + 255) / 256, 256, 0, stream>>>(X, Xhi, Xlo);
    k_moments<<<128, 128, 0, stream>>>(X, sq, m1, m1 + D);
    k_thresh <<<N, 64, 0, stream>>>(X, sq, m1, m1 + D, Tthr);

    for (int R0 = 0; R0 < N; R0 += band) {
        int rows = min(band, N - R0);
        dim3 g(N / 128, rows / 128);
        k_distm <<<g, 256, 0, stream>>>(Xhi, Xlo, sq, d2band, R0);
        k_filter<<<rows, 256, 0, stream>>>(d2band, R0, Tthr, cnt, rowbuf, capb);
    }

    k_sel2    <<<N, 64, 0, stream>>>(rowbuf, cnt, knn, density, flagged, nflag, capb);
    k_fallback<<<64, 256, 0, stream>>>(X, sq, nflag, flagged, knn, density);

    k_setbits<<<(N * KNN + 255) / 256, 256, 0, stream>>>(knn, bits);
    k_rowsum <<<(N + 255) / 256, 256, 0, stream>>>(knn, density, numer, cntb);
    k_rev    <<<(N * KNN + 255) / 256, 256, 0, stream>>>(knn, density, bits, numer, cntb);

    k_final  <<<(N + 255) / 256, 256, 0, stream>>>(density, numer, cntb, logits, out);
}

// Round 6
// 228.389 us; speedup vs baseline: 2.6912x; 1.2038x over previous
//
#include <hip/hip_runtime.h>
#include <cstdint>
#include <cstddef>

#define N 8192
#define D 128
#define KNN 20
#define NC 10
#define CAPB 448          // max survivor entries per row (k_sel2 register budget: 7*64)
#define SLOTS 16          // per-row LDS survivor slots per block (lambda~2.3, P(>16)~1e-9)
#define ZTH 2.1f          // threshold z-score (expected ~146 survivors/row)
#define NW (N / 32)       // bitmap words per row
constexpr float EPS = 1e-10f;

typedef __attribute__((ext_vector_type(8))) short short8;
typedef __attribute__((ext_vector_type(4))) float f32x4;

// bf16 round-to-nearest-even, pure bit ops
__device__ inline unsigned short f32_to_bf16_rne(float x) {
    unsigned u = __float_as_uint(x);
    unsigned r = u + 0x7FFFu + ((u >> 16) & 1u);
    return (unsigned short)(r >> 16);
}
__device__ inline float bf16_to_f32(unsigned short h) {
    return __uint_as_float((unsigned)h << 16);
}
__device__ inline unsigned long long pack_key(float d, int j) {
    return ((unsigned long long)__float_as_uint(d) << 14) | (unsigned long long)(j + 1);
}

// ---------------- K1: squared norms (exact fp32) ----------------
__global__ void k_sqnorm(const float* __restrict__ X, float* __restrict__ sq) {
    int row = blockIdx.x;
    int lane = threadIdx.x;
    const float2* X2 = (const float2*)(X + (size_t)row * D);
    float2 a = X2[lane];
    float s = a.x * a.x + a.y * a.y;
    #pragma unroll
    for (int off = 32; off; off >>= 1) s += __shfl_down(s, off, 64);
    if (lane == 0) sq[row] = s;
}

// ---------------- K2: split X into bf16 hi + lo ----------------
__global__ void k_split(const float* __restrict__ X, unsigned short* __restrict__ Xhi,
                        unsigned short* __restrict__ Xlo) {
    int i = blockIdx.x * 256 + threadIdx.x;     // 1M elems / 4
    const float4* X4 = (const float4*)X;
    float4 x = X4[i];
    unsigned short h[4], l[4];
    float xs[4] = {x.x, x.y, x.z, x.w};
    #pragma unroll
    for (int q = 0; q < 4; ++q) {
        h[q] = f32_to_bf16_rne(xs[q]);
        float hf = bf16_to_f32(h[q]);
        l[q] = f32_to_bf16_rne(xs[q] - hf);
    }
    *(ushort4*)&Xhi[(size_t)i * 4] = make_ushort4(h[0], h[1], h[2], h[3]);
    *(ushort4*)&Xlo[(size_t)i * 4] = make_ushort4(l[0], l[1], l[2], l[3]);
}

// ---------------- K2b: data moments (col sums, sum sq, sum sq^2) ----------------
__global__ __launch_bounds__(128) void k_moments(const float* __restrict__ X,
                                                 const float* __restrict__ sq,
                                                 float* __restrict__ m1,
                                                 float* __restrict__ msc) {
    int b = blockIdx.x, t = threadIdx.x;        // 128 blocks x 128 threads, 64 rows each
    int r0 = b * 64;
    float s1 = 0.f;
    for (int r = 0; r < 64; ++r) s1 += X[(size_t)(r0 + r) * D + t];
    atomicAdd(&m1[t], s1);
    if (t < 64) {                               // wave 0
        float s = sq[r0 + t];
        float ss1 = s, ss2 = s * s;
        #pragma unroll
        for (int off = 32; off; off >>= 1) {
            ss1 += __shfl_down(ss1, off, 64);
            ss2 += __shfl_down(ss2, off, 64);
        }
        if (t == 0) { atomicAdd(&msc[0], ss1); atomicAdd(&msc[1], ss2); }
    }
}

// ---------------- K2c: per-row analytic survivor threshold ----------------
// mu_i = sq_i + E[sq] - 2 x_i . mean(x);  var_i = Var[sq] + 4 sq_i
__global__ void k_thresh(const float* __restrict__ X, const float* __restrict__ sq,
                         const float* __restrict__ m1, const float* __restrict__ msc,
                         float* __restrict__ T) {
    int row = blockIdx.x, lane = threadIdx.x;   // 64 lanes
    const float2* X2 = (const float2*)(X + (size_t)row * D);
    const float2* M2 = (const float2*)m1;
    float2 a = X2[lane], m = M2[lane];
    float dotp = a.x * m.x + a.y * m.y;
    #pragma unroll
    for (int off = 32; off; off >>= 1) dotp += __shfl_down(dotp, off, 64);
    if (lane == 0) {
        const float invN = 1.f / N;
        float Esq   = msc[0] * invN;
        float Esq2  = msc[1] * invN;
        float varSq = fmaxf(Esq2 - Esq * Esq, 0.f);
        float s  = sq[row];
        float mu = s + Esq - 2.f * dotp * invN;
        float var = varSq + 4.f * s;
        T[row] = mu - ZTH * sqrtf(var);
    }
}

// ---------------- K3: fused MFMA distance + threshold filter ----------------
// 128x128 tile, full matrix (each row owned by its tile-row blocks). Same
// per-element MFMA sequence as the verified kernels -> bit-identical d2.
// Epilogue: per-row LDS aggregation; ONE global atomic per row per block
// (R3 lesson: never a dependent global atomic per survivor).
#define ASTRIDE 40   // bf16 elems per LDS row (32 data + 8 pad); 80 B, 16B-aligned
struct StageS {
    unsigned short Ahi[128 * ASTRIDE];
    unsigned short Alo[128 * ASTRIDE];
    unsigned short Bhi[128 * ASTRIDE];
    unsigned short Blo[128 * ASTRIDE];
};
struct EpiS {
    unsigned long long slots[128 * SLOTS];
    unsigned rc[128];
    unsigned rbase[128];
};
__global__ __launch_bounds__(256, 3) void k_distf2(
        const unsigned short* __restrict__ Xhi, const unsigned short* __restrict__ Xlo,
        const float* __restrict__ sqn, const float* __restrict__ Tthr,
        int* __restrict__ cnt, unsigned long long* __restrict__ rowbuf, int capb) {
    __shared__ alignas(16) union { StageS s; EpiS e; } U;

    const int t    = threadIdx.x;
    const int lane = t & 63;
    const int w    = t >> 6;
    const int wr   = w >> 1;          // 0..1 : 64-row half
    const int wc   = w & 1;           // 0..1 : 64-col half
    const int lrow = lane & 15;       // fragment row within 16
    const int lkg  = lane >> 4;       // 0..3 : k-group (8 bf16 each)

    const int rowTile = blockIdx.y * 128;
    const int colTile = blockIdx.x * 128;

    f32x4 acc[4][4];
    #pragma unroll
    for (int i = 0; i < 4; ++i)
        #pragma unroll
        for (int j = 0; j < 4; ++j) acc[i][j] = (f32x4){0.f, 0.f, 0.f, 0.f};

    for (int kc = 0; kc < 4; ++kc) {            // four K-chunks of 32
        const int kb = kc * 32;
        __syncthreads();
        #pragma unroll
        for (int p = 0; p < 2; ++p) {           // stage A (128 rows): 512 chunks/256thr
            int u = t + 256 * p, r = u >> 2, c = u & 3;
            size_t g = (size_t)(rowTile + r) * 128 + kb + c * 8;
            *(uint4*)&U.s.Ahi[r * ASTRIDE + c * 8] = *(const uint4*)&Xhi[g];
            *(uint4*)&U.s.Alo[r * ASTRIDE + c * 8] = *(const uint4*)&Xlo[g];
        }
        #pragma unroll
        for (int p = 0; p < 2; ++p) {           // stage B (128 rows)
            int u = t + 256 * p, r = u >> 2, c = u & 3;
            size_t g = (size_t)(colTile + r) * 128 + kb + c * 8;
            *(uint4*)&U.s.Bhi[r * ASTRIDE + c * 8] = *(const uint4*)&Xhi[g];
            *(uint4*)&U.s.Blo[r * ASTRIDE + c * 8] = *(const uint4*)&Xlo[g];
        }
        __syncthreads();

        short8 a[4], b[4];
        // pass 1: hi . hi
        #pragma unroll
        for (int i = 0; i < 4; ++i)
            a[i] = *(const short8*)&U.s.Ahi[(wr * 64 + 16 * i + lrow) * ASTRIDE + lkg * 8];
        #pragma unroll
        for (int j = 0; j < 4; ++j)
            b[j] = *(const short8*)&U.s.Bhi[(wc * 64 + 16 * j + lrow) * ASTRIDE + lkg * 8];
        #pragma unroll
        for (int i = 0; i < 4; ++i)
            #pragma unroll
            for (int j = 0; j < 4; ++j)
                acc[i][j] = __builtin_amdgcn_mfma_f32_16x16x32_bf16(a[i], b[j], acc[i][j], 0, 0, 0);
        // pass 2: hi . lo   (reload b only)
        #pragma unroll
        for (int j = 0; j < 4; ++j)
            b[j] = *(const short8*)&U.s.Blo[(wc * 64 + 16 * j + lrow) * ASTRIDE + lkg * 8];
        #pragma unroll
        for (int i = 0; i < 4; ++i)
            #pragma unroll
            for (int j = 0; j < 4; ++j)
                acc[i][j] = __builtin_amdgcn_mfma_f32_16x16x32_bf16(a[i], b[j], acc[i][j], 0, 0, 0);
        // pass 3: lo . hi   (reload both)
        #pragma unroll
        for (int i = 0; i < 4; ++i)
            a[i] = *(const short8*)&U.s.Alo[(wr * 64 + 16 * i + lrow) * ASTRIDE + lkg * 8];
        #pragma unroll
        for (int j = 0; j < 4; ++j)
            b[j] = *(const short8*)&U.s.Bhi[(wc * 64 + 16 * j + lrow) * ASTRIDE + lkg * 8];
        #pragma unroll
        for (int i = 0; i < 4; ++i)
            #pragma unroll
            for (int j = 0; j < 4; ++j)
                acc[i][j] = __builtin_amdgcn_mfma_f32_16x16x32_bf16(a[i], b[j], acc[i][j], 0, 0, 0);
    }

    // ---- fused epilogue: per-row LDS survivor aggregation ----
    __syncthreads();                            // staging LDS dead; overlay epilogue
    if (t < 128) U.e.rc[t] = 0;
    __syncthreads();

    // C/D layout col=lane&15, row=(lane>>4)*4+reg  [m89/m91]
    float sqb[4]; int gcol[4];
    #pragma unroll
    for (int j = 0; j < 4; ++j) {
        gcol[j] = colTile + wc * 64 + 16 * j + lrow;
        sqb[j]  = sqn[gcol[j]];
    }
    #pragma unroll
    for (int i = 0; i < 4; ++i) {
        int lr0 = wr * 64 + 16 * i + lkg * 4;   // block-local row (reg 0)
        #pragma unroll
        for (int q = 0; q < 4; ++q) {
            int lr = lr0 + q;
            float sa = sqn[rowTile + lr];
            float Ti = Tthr[rowTile + lr];
            #pragma unroll
            for (int j = 0; j < 4; ++j) {
                float d = fmaxf(fmaf(-2.f, acc[i][j][q], sa + sqb[j]), 0.f);
                if (d < Ti) {
                    unsigned o = atomicAdd(&U.e.rc[lr], 1u);
                    if (o < SLOTS) U.e.slots[lr * SLOTS + o] = pack_key(d, gcol[j]);
                }
            }
        }
    }
    __syncthreads();
    if (t < 128) {                              // one global atomic per row
        unsigned nr = U.e.rc[t];
        if (nr > SLOTS) {                       // ~never: force exact fallback for row
            atomicAdd(&cnt[rowTile + t], capb + 1);
            U.e.rbase[t] = 0xFFFFFFFFu;
        } else if (nr > 0) {
            U.e.rbase[t] = (unsigned)atomicAdd(&cnt[rowTile + t], (int)nr);
        } else {
            U.e.rbase[t] = 0;
        }
    }
    __syncthreads();
    #pragma unroll
    for (int it = 0; it < (128 * SLOTS) / 256; ++it) {   // coalesced flush
        int idx = t + 256 * it;
        int r = idx / SLOTS, s = idx % SLOTS;
        unsigned nr = U.e.rc[r], base = U.e.rbase[r];
        if ((unsigned)s < min(nr, (unsigned)SLOTS) && base != 0xFFFFFFFFu) {
            unsigned pos = base + (unsigned)s;
            if (pos < (unsigned)capb)           // pos>=capb only when cnt>capb -> fallback
                rowbuf[(size_t)(rowTile + r) * capb + pos] = U.e.slots[idx];
        }
    }
}

// ---------------- K4: exact top-20 from survivor buffer ----------------
__global__ __launch_bounds__(64) void k_sel2(const unsigned long long* __restrict__ rowbuf,
                                             const int* __restrict__ cnt,
                                             int* __restrict__ knn_idx,
                                             float* __restrict__ density,
                                             int* __restrict__ flagged,
                                             int* __restrict__ nflag, int capb) {
    int row = blockIdx.x, t = threadIdx.x;
    int n = cnt[row];
    if (n < KNN || n > capb) {                  // model miss: exact fallback handles it
        if (t == 0) { int p = atomicAdd(nflag, 1); flagged[p] = row; }
        return;
    }
    const unsigned long long* rb = rowbuf + (size_t)row * capb;
    unsigned long long v[7];                    // 7*64 = 448 >= capb
    #pragma unroll
    for (int k = 0; k < 7; ++k) { int idx = t + 64 * k; v[k] = idx < n ? rb[idx] : ~0ull; }
    unsigned long long last = 0ull;
    float sumd = 0.f;
    for (int r = 0; r < KNN; ++r) {
        unsigned long long m = ~0ull;
        #pragma unroll
        for (int k = 0; k < 7; ++k) if (v[k] > last && v[k] < m) m = v[k];
        #pragma unroll
        for (int off = 32; off; off >>= 1) {
            unsigned long long o = __shfl_down(m, off, 64);
            if (o < m) m = o;
        }
        m = __shfl(m, 0, 64);
        last = m;
        if (t == 0) {
            int j = (int)(m & 16383ull) - 1;
            if (j < 0) j = 0; if (j >= N) j = N - 1;
            knn_idx[(size_t)row * KNN + r] = j;
            sumd += sqrtf(__uint_as_float((unsigned)(m >> 14)));
        }
    }
    if (t == 0) density[row] = 1.f / (sumd * (1.f / KNN) + EPS);
}

// ---------------- K4b: exact fp32 brute-force fallback for flagged rows -------
__global__ __launch_bounds__(256) void k_fallback(const float* __restrict__ X,
                                                  const float* __restrict__ sq,
                                                  const int* __restrict__ nflag,
                                                  const int* __restrict__ flagged,
                                                  int* __restrict__ knn_idx,
                                                  float* __restrict__ density) {
    __shared__ float xr[D];
    __shared__ unsigned long long red[256];
    int t = threadIdx.x;
    int nf = *nflag;
    for (int f = blockIdx.x; f < nf; f += gridDim.x) {
        int row = flagged[f];
        __syncthreads();
        if (t < D) xr[t] = X[(size_t)row * D + t];
        __syncthreads();
        float sqr = sq[row];
        unsigned long long keys[32];
        for (int i = 0; i < 32; ++i) {
            int col = t + 256 * i;
            const float4* cp = (const float4*)(X + (size_t)col * D);
            float dot = 0.f;
            #pragma unroll
            for (int d4 = 0; d4 < 32; ++d4) {
                float4 c = cp[d4];
                float4 x = *(const float4*)&xr[d4 * 4];
                dot = fmaf(c.x, x.x, dot); dot = fmaf(c.y, x.y, dot);
                dot = fmaf(c.z, x.z, dot); dot = fmaf(c.w, x.w, dot);
            }
            float d2v = fmaxf(sqr + sq[col] - 2.f * dot, 0.f);
            keys[i] = pack_key(d2v, col);
        }
        unsigned long long last = 0ull;
        float sumd = 0.f;
        for (int r = 0; r < KNN; ++r) {
            unsigned long long m = ~0ull;
            #pragma unroll
            for (int i = 0; i < 32; ++i) if (keys[i] > last && keys[i] < m) m = keys[i];
            red[t] = m; __syncthreads();
            for (int s = 128; s; s >>= 1) {
                if (t < s && red[t + s] < red[t]) red[t] = red[t + s];
                __syncthreads();
            }
            m = red[0]; __syncthreads();
            last = m;
            if (t == 0) {
                int j = (int)(m & 16383ull) - 1;
                if (j < 0) j = 0; if (j >= N) j = N - 1;
                knn_idx[(size_t)row * KNN + r] = j;
                sumd += sqrtf(__uint_as_float((unsigned)(m >> 14)));
            }
        }
        if (t == 0) density[row] = 1.f / (sumd * (1.f / KNN) + EPS);
    }
}

// ---------------- K5a: kNN membership bitmap (exact) ----------------
__global__ void k_setbits(const int* __restrict__ knn_idx, unsigned* __restrict__ bits) {
    int p = blockIdx.x * 256 + threadIdx.x;
    if (p >= N * KNN) return;
    int i = p / KNN;
    int j = knn_idx[p];
    atomicOr(&bits[(size_t)i * NW + (j >> 5)], 1u << (j & 31));
}

// ---------------- K5b: forward kNN sums (row-owned, zero atomics) ------------
__global__ void k_rowsum(const int* __restrict__ knn_idx, const float* __restrict__ density,
                         float* __restrict__ numer, float* __restrict__ cntb) {
    int i = blockIdx.x * 256 + threadIdx.x;
    if (i >= N) return;
    const int* ki = knn_idx + (size_t)i * KNN;
    float s = 0.f;
    #pragma unroll
    for (int m = 0; m < KNN; ++m) s += density[ki[m]];
    numer[i] = s;
    cntb[i] = (float)KNN;
}

// ---------------- K5c: reverse non-mutual contributions (bitmap test) --------
__global__ void k_rev(const int* __restrict__ knn_idx, const float* __restrict__ density,
                      const unsigned* __restrict__ bits,
                      float* __restrict__ numer, float* __restrict__ cntb) {
    int p = blockIdx.x * 256 + threadIdx.x;
    if (p >= N * KNN) return;
    int i = p / KNN;
    int j = knn_idx[p];
    unsigned wd = bits[(size_t)j * NW + (i >> 5)];
    if (!(wd & (1u << (i & 31)))) {             // i not in knn(j): non-mutual edge
        atomicAdd(&numer[j], density[i]);
        atomicAdd(&cntb[j], 1.f);
    }
}

// ---------------- K6: scores, flags, class preds ----------------
__global__ void k_final(const float* __restrict__ density, const float* __restrict__ numer,
                        const float* __restrict__ cntb, const float* __restrict__ logits,
                        float* __restrict__ out) {
    int i = blockIdx.x * 256 + threadIdx.x;
    if (i >= N) return;
    float c     = fmaxf(cntb[i], 1.f);
    float avg   = numer[i] / c;
    float score = -(density[i] / (avg + EPS));
    out[i] = score;
    bool flag = score < -0.5f;
    out[N + i] = flag ? 1.f : 0.f;
    const float* lg = logits + (size_t)i * NC;
    float best = lg[0]; int bi = 0;
    #pragma unroll
    for (int k = 1; k < NC; ++k) { float x = lg[k]; if (x > best) { best = x; bi = k; } }
    out[2 * N + i] = flag ? -1.f : (float)bi;
}

extern "C" void kernel_launch(void* const* d_in, const int* in_sizes, int n_in,
                              void* d_out, int out_size, void* d_ws, size_t ws_size,
                              hipStream_t stream) {
    const float* X      = (const float*)d_in[0];
    const float* logits = (const float*)d_in[1];
    float* out = (float*)d_out;

    char* w = (char*)d_ws;
    auto alloc = [&](size_t bytes) { char* p = w; w += (bytes + 255) & ~(size_t)255; return p; };
    float* sq      = (float*)alloc((size_t)N * 4);
    float* density = (float*)alloc((size_t)N * 4);
    float* numer   = (float*)alloc((size_t)N * 4);
    float* cntb    = (float*)alloc((size_t)N * 4);
    int*   knn     = (int*)alloc((size_t)N * KNN * 4);
    unsigned short* Xhi = (unsigned short*)alloc((size_t)N * D * 2);
    unsigned short* Xlo = (unsigned short*)alloc((size_t)N * D * 2);
    float* Tthr    = (float*)alloc((size_t)N * 4);
    float* m1      = (float*)alloc((size_t)(D + 2) * 4);
    int*   cnt     = (int*)alloc((size_t)N * 4);
    int*   flagged = (int*)alloc((size_t)N * 4);
    int*   nflag   = (int*)alloc(256);
    unsigned* bits = (unsigned*)alloc((size_t)N * NW * 4);   // 8 MB kNN bitmap

    size_t used  = (size_t)(w - (char*)d_ws);
    size_t avail = ws_size > used ? ws_size - used : 0;
    int capb = (int)(avail / ((size_t)N * 8));
    if (capb > CAPB) capb = CAPB;
    if (capb < 1) capb = 1;                     // degenerate: all rows -> exact fallback
    unsigned long long* rowbuf = (unsigned long long*)alloc((size_t)N * capb * 8);

    hipMemsetAsync(bits,  0, (size_t)N * NW * 4, stream);
    hipMemsetAsync(cnt,   0, (size_t)N * 4, stream);
    hipMemsetAsync(m1,    0, (size_t)(D + 2) * 4, stream);
    hipMemsetAsync(nflag, 0, 4, stream);

    k_sqnorm <<<N, 64, 0, stream>>>(X, sq);
    k_split  <<<(N * D / 4 + 255) / 256, 256, 0, stream>>>(X, Xhi, Xlo);
    k_moments<<<128, 128, 0, stream>>>(X, sq, m1, m1 + D);
    k_thresh <<<N, 64, 0, stream>>>(X, sq, m1, m1 + D, Tthr);

    k_distf2 <<<dim3(N / 128, N / 128), 256, 0, stream>>>(Xhi, Xlo, sq, Tthr, cnt, rowbuf, capb);

    k_sel2    <<<N, 64, 0, stream>>>(rowbuf, cnt, knn, density, flagged, nflag, capb);
    k_fallback<<<64, 256, 0, stream>>>(X, sq, nflag, flagged, knn, density);

    k_setbits<<<(N * KNN + 255) / 256, 256, 0, stream>>>(knn, bits);
    k_rowsum <<<(N + 255) / 256, 256, 0, stream>>>(knn, density, numer, cntb);
    k_rev    <<<(N * KNN + 255) / 256, 256, 0, stream>>>(knn, density, bits, numer, cntb);

    k_final  <<<(N + 255) / 256, 256, 0, stream>>>(density, numer, cntb, logits, out);
}

// Round 7
// 205.528 us; speedup vs baseline: 2.9905x; 1.1112x over previous
//
#include <hip/hip_runtime.h>
#include <cstdint>
#include <cstddef>

#define N 8192
#define D 128
#define KNN 20
#define NC 10
#define CAPB 448          // max survivor entries per row (k_sel2 register budget: 7*64)
#define SLOTS 16          // per-pool LDS survivor slots per block (lambda~2.3, P(>16)~1e-10)
#define ZTH 2.1f          // threshold z-score (expected ~146 survivors/row)
#define NW (N / 32)       // bitmap words per row
#define NT 64             // 128-wide tiles per dim
#define NBLK (NT * (NT + 1) / 2)   // 2080 upper-triangle tiles
constexpr float EPS = 1e-10f;

typedef __attribute__((ext_vector_type(8))) short short8;
typedef __attribute__((ext_vector_type(4))) float f32x4;

__device__ inline unsigned short f32_to_bf16_rne(float x) {
    unsigned u = __float_as_uint(x);
    unsigned r = u + 0x7FFFu + ((u >> 16) & 1u);
    return (unsigned short)(r >> 16);
}
__device__ inline float bf16_to_f32(unsigned short h) {
    return __uint_as_float((unsigned)h << 16);
}
__device__ inline unsigned long long pack_key(float d, int j) {
    return ((unsigned long long)__float_as_uint(d) << 14) | (unsigned long long)(j + 1);
}

// ---------------- K1: fused sqnorm + bf16 hi/lo split (per row) ----------------
__global__ void k_prep(const float* __restrict__ X, unsigned short* __restrict__ Xhi,
                       unsigned short* __restrict__ Xlo, float* __restrict__ sq) {
    int row = blockIdx.x, t = threadIdx.x;      // 64 lanes
    const float2* X2 = (const float2*)(X + (size_t)row * D);
    float2 a = X2[t];
    ushort2 h, l;
    h.x = f32_to_bf16_rne(a.x); l.x = f32_to_bf16_rne(a.x - bf16_to_f32(h.x));
    h.y = f32_to_bf16_rne(a.y); l.y = f32_to_bf16_rne(a.y - bf16_to_f32(h.y));
    *(ushort2*)&Xhi[(size_t)row * D + 2 * t] = h;
    *(ushort2*)&Xlo[(size_t)row * D + 2 * t] = l;
    float s = a.x * a.x + a.y * a.y;
    #pragma unroll
    for (int off = 32; off; off >>= 1) s += __shfl_down(s, off, 64);
    if (t == 0) sq[row] = s;
}

// ---------------- K2b: data moments (col sums, sum sq, sum sq^2) ----------------
__global__ __launch_bounds__(128) void k_moments(const float* __restrict__ X,
                                                 const float* __restrict__ sq,
                                                 float* __restrict__ m1,
                                                 float* __restrict__ msc) {
    int b = blockIdx.x, t = threadIdx.x;        // 512 blocks x 128 threads, 16 rows each
    int r0 = b * 16;
    float s1 = 0.f;
    #pragma unroll
    for (int r = 0; r < 16; ++r) s1 += X[(size_t)(r0 + r) * D + t];
    atomicAdd(&m1[t], s1);
    if (t < 16) {
        float s = sq[r0 + t];
        float ss1 = s, ss2 = s * s;
        #pragma unroll
        for (int off = 8; off; off >>= 1) {
            ss1 += __shfl_down(ss1, off, 64);
            ss2 += __shfl_down(ss2, off, 64);
        }
        if (t == 0) { atomicAdd(&msc[0], ss1); atomicAdd(&msc[1], ss2); }
    }
}

// ---------------- K2c: per-row analytic survivor threshold ----------------
__global__ void k_thresh(const float* __restrict__ X, const float* __restrict__ sq,
                         const float* __restrict__ m1, const float* __restrict__ msc,
                         float* __restrict__ T) {
    int row = blockIdx.x, lane = threadIdx.x;   // 64 lanes
    const float2* X2 = (const float2*)(X + (size_t)row * D);
    const float2* M2 = (const float2*)m1;
    float2 a = X2[lane], m = M2[lane];
    float dotp = a.x * m.x + a.y * m.y;
    #pragma unroll
    for (int off = 32; off; off >>= 1) dotp += __shfl_down(dotp, off, 64);
    if (lane == 0) {
        const float invN = 1.f / N;
        float Esq   = msc[0] * invN;
        float Esq2  = msc[1] * invN;
        float varSq = fmaxf(Esq2 - Esq * Esq, 0.f);
        float s  = sq[row];
        float mu = s + Esq - 2.f * dotp * invN;
        float var = varSq + 4.f * s;
        T[row] = mu - ZTH * sqrtf(var);
    }
}

// ---------------- K3: fused MFMA distance + filter, upper-triangle ----------
// 2080 tiles (bx>=by). Each block pushes survivors for its 128 "row" rows AND
// (transposed, reusing the symmetric acc) its 128 "col" rows into per-row LDS
// pools; one global atomic per pool per block (R6-proven epilogue pattern).
// Same per-element MFMA sequence (hi.hi, hi.lo, lo.hi per kc) -> d2 values
// identical to all prior verified kernels. b_hi cached in regs (ds_read -20%).
#define ASTRIDE 40   // bf16 elems per LDS row (32 data + 8 pad); 80 B, 16B-aligned
struct StageS {
    unsigned short Ahi[128 * ASTRIDE];
    unsigned short Alo[128 * ASTRIDE];
    unsigned short Bhi[128 * ASTRIDE];
    unsigned short Blo[128 * ASTRIDE];
};
struct EpiS {
    unsigned long long slots[256 * SLOTS];   // 32 KB
    unsigned rc[256];
    unsigned rbase[256];
};
__global__ __launch_bounds__(256, 3) void k_distf3(
        const unsigned short* __restrict__ Xhi, const unsigned short* __restrict__ Xlo,
        const float* __restrict__ sqn, const float* __restrict__ Tthr,
        int* __restrict__ cnt, unsigned long long* __restrict__ rowbuf, int capb) {
    // linear block -> upper-triangle tile (by <= bx)
    int rem = blockIdx.x, by = 0;
    while (rem >= NT - by) { rem -= NT - by; ++by; }
    const int bx = by + rem;

    __shared__ alignas(16) union { StageS s; EpiS e; } U;

    const int t    = threadIdx.x;
    const int lane = t & 63;
    const int w    = t >> 6;
    const int wr   = w >> 1;          // 0..1 : 64-row half
    const int wc   = w & 1;           // 0..1 : 64-col half
    const int lrow = lane & 15;       // fragment row within 16
    const int lkg  = lane >> 4;       // 0..3 : k-group (8 bf16 each)

    const int rowTile = by * 128;
    const int colTile = bx * 128;

    f32x4 acc[4][4];
    #pragma unroll
    for (int i = 0; i < 4; ++i)
        #pragma unroll
        for (int j = 0; j < 4; ++j) acc[i][j] = (f32x4){0.f, 0.f, 0.f, 0.f};

    for (int kc = 0; kc < 4; ++kc) {            // four K-chunks of 32
        const int kb = kc * 32;
        __syncthreads();
        #pragma unroll
        for (int p = 0; p < 2; ++p) {           // stage A (128 rows)
            int u = t + 256 * p, r = u >> 2, c = u & 3;
            size_t g = (size_t)(rowTile + r) * 128 + kb + c * 8;
            *(uint4*)&U.s.Ahi[r * ASTRIDE + c * 8] = *(const uint4*)&Xhi[g];
            *(uint4*)&U.s.Alo[r * ASTRIDE + c * 8] = *(const uint4*)&Xlo[g];
        }
        #pragma unroll
        for (int p = 0; p < 2; ++p) {           // stage B (128 rows)
            int u = t + 256 * p, r = u >> 2, c = u & 3;
            size_t g = (size_t)(colTile + r) * 128 + kb + c * 8;
            *(uint4*)&U.s.Bhi[r * ASTRIDE + c * 8] = *(const uint4*)&Xhi[g];
            *(uint4*)&U.s.Blo[r * ASTRIDE + c * 8] = *(const uint4*)&Xlo[g];
        }
        __syncthreads();

        short8 a[4], bh[4], bl[4];
        #pragma unroll
        for (int i = 0; i < 4; ++i)
            a[i] = *(const short8*)&U.s.Ahi[(wr * 64 + 16 * i + lrow) * ASTRIDE + lkg * 8];
        #pragma unroll
        for (int j = 0; j < 4; ++j)
            bh[j] = *(const short8*)&U.s.Bhi[(wc * 64 + 16 * j + lrow) * ASTRIDE + lkg * 8];
        #pragma unroll
        for (int j = 0; j < 4; ++j)
            bl[j] = *(const short8*)&U.s.Blo[(wc * 64 + 16 * j + lrow) * ASTRIDE + lkg * 8];
        // pass 1: hi . hi
        #pragma unroll
        for (int i = 0; i < 4; ++i)
            #pragma unroll
            for (int j = 0; j < 4; ++j)
                acc[i][j] = __builtin_amdgcn_mfma_f32_16x16x32_bf16(a[i], bh[j], acc[i][j], 0, 0, 0);
        // pass 2: hi . lo
        #pragma unroll
        for (int i = 0; i < 4; ++i)
            #pragma unroll
            for (int j = 0; j < 4; ++j)
                acc[i][j] = __builtin_amdgcn_mfma_f32_16x16x32_bf16(a[i], bl[j], acc[i][j], 0, 0, 0);
        // pass 3: lo . hi (a reload; bh reused from regs)
        #pragma unroll
        for (int i = 0; i < 4; ++i)
            a[i] = *(const short8*)&U.s.Alo[(wr * 64 + 16 * i + lrow) * ASTRIDE + lkg * 8];
        #pragma unroll
        for (int i = 0; i < 4; ++i)
            #pragma unroll
            for (int j = 0; j < 4; ++j)
                acc[i][j] = __builtin_amdgcn_mfma_f32_16x16x32_bf16(a[i], bh[j], acc[i][j], 0, 0, 0);
    }

    // ---- epilogue: dual-pool LDS survivor aggregation ----
    __syncthreads();                            // staging LDS dead; overlay epilogue
    U.e.rc[t] = 0;
    __syncthreads();

    // C/D layout col=lane&15, row=(lane>>4)*4+reg  [m89/m91]
    float sqb[4], Tb[4]; int gcol[4], lcol[4];
    #pragma unroll
    for (int j = 0; j < 4; ++j) {
        lcol[j] = wc * 64 + 16 * j + lrow;
        gcol[j] = colTile + lcol[j];
        sqb[j]  = sqn[gcol[j]];
        Tb[j]   = Tthr[gcol[j]];
    }
    #pragma unroll
    for (int i = 0; i < 4; ++i) {
        int lr0 = wr * 64 + 16 * i + lkg * 4;
        #pragma unroll
        for (int q = 0; q < 4; ++q) {
            int lr = lr0 + q, gi = rowTile + lr;
            float sa = sqn[gi];
            float Ti = Tthr[gi];
            #pragma unroll
            for (int j = 0; j < 4; ++j) {
                float d = fmaxf(fmaf(-2.f, acc[i][j][q], sa + sqb[j]), 0.f);
                int gj = gcol[j];
                if (gj >= gi && d < Ti) {       // forward: row gi gets (d, gj)
                    unsigned o = atomicAdd(&U.e.rc[lr], 1u);
                    if (o < SLOTS) U.e.slots[lr * SLOTS + o] = pack_key(d, gj);
                }
                if (gj > gi && d < Tb[j]) {     // transpose: row gj gets (d, gi)
                    unsigned o = atomicAdd(&U.e.rc[128 + lcol[j]], 1u);
                    if (o < SLOTS) U.e.slots[(128 + lcol[j]) * SLOTS + o] = pack_key(d, gi);
                }
            }
        }
    }
    __syncthreads();
    {                                           // one global atomic per pool
        unsigned nr = U.e.rc[t];
        int grow = (t < 128) ? (rowTile + t) : (colTile + (t - 128));
        if (nr > SLOTS) {                       // ~never: force exact fallback
            atomicAdd(&cnt[grow], capb + 1);
            U.e.rbase[t] = 0xFFFFFFFFu;
        } else if (nr > 0) {
            U.e.rbase[t] = (unsigned)atomicAdd(&cnt[grow], (int)nr);
        } else {
            U.e.rbase[t] = 0;
        }
    }
    __syncthreads();
    #pragma unroll
    for (int it = 0; it < (256 * SLOTS) / 256; ++it) {   // coalesced flush
        int idx = t + 256 * it;
        int r = idx >> 4, s = idx & 15;
        unsigned nr = U.e.rc[r], base = U.e.rbase[r];
        if ((unsigned)s < min(nr, (unsigned)SLOTS) && base != 0xFFFFFFFFu) {
            unsigned pos = base + (unsigned)s;
            int grow = (r < 128) ? (rowTile + r) : (colTile + (r - 128));
            if (pos < (unsigned)capb)
                rowbuf[(size_t)grow * capb + pos] = U.e.slots[r * SLOTS + s];
        }
    }
}

// ---------------- K4: exact top-20 from survivor buffer (+ bitmap set) --------
__global__ __launch_bounds__(64) void k_sel2(const unsigned long long* __restrict__ rowbuf,
                                             const int* __restrict__ cnt,
                                             int* __restrict__ knn_idx,
                                             float* __restrict__ density,
                                             unsigned* __restrict__ bits,
                                             int* __restrict__ flagged,
                                             int* __restrict__ nflag, int capb) {
    __shared__ int nb[KNN];
    int row = blockIdx.x, t = threadIdx.x;
    int n = cnt[row];
    if (n < KNN || n > capb) {                  // model miss: exact fallback handles it
        if (t == 0) { int p = atomicAdd(nflag, 1); flagged[p] = row; }
        return;
    }
    const unsigned long long* rb = rowbuf + (size_t)row * capb;
    unsigned long long v[7];                    // 7*64 = 448 >= capb
    #pragma unroll
    for (int k = 0; k < 7; ++k) { int idx = t + 64 * k; v[k] = idx < n ? rb[idx] : ~0ull; }
    unsigned long long last = 0ull;
    float sumd = 0.f;
    for (int r = 0; r < KNN; ++r) {
        unsigned long long m = ~0ull;
        #pragma unroll
        for (int k = 0; k < 7; ++k) if (v[k] > last && v[k] < m) m = v[k];
        #pragma unroll
        for (int off = 32; off; off >>= 1) {
            unsigned long long o = __shfl_down(m, off, 64);
            if (o < m) m = o;
        }
        m = __shfl(m, 0, 64);
        last = m;
        if (t == 0) {
            int j = (int)(m & 16383ull) - 1;
            if (j < 0) j = 0; if (j >= N) j = N - 1;
            knn_idx[(size_t)row * KNN + r] = j;
            nb[r] = j;
            sumd += sqrtf(__uint_as_float((unsigned)(m >> 14)));
        }
    }
    if (t == 0) density[row] = 1.f / (sumd * (1.f / KNN) + EPS);
    __syncthreads();
    if (t < KNN) {
        int j = nb[t];
        atomicOr(&bits[(size_t)row * NW + (j >> 5)], 1u << (j & 31));
    }
}

// ---------------- K4b: exact fp32 brute-force fallback for flagged rows -------
__global__ __launch_bounds__(256) void k_fallback(const float* __restrict__ X,
                                                  const float* __restrict__ sq,
                                                  const int* __restrict__ nflag,
                                                  const int* __restrict__ flagged,
                                                  int* __restrict__ knn_idx,
                                                  float* __restrict__ density,
                                                  unsigned* __restrict__ bits) {
    __shared__ float xr[D];
    __shared__ unsigned long long red[256];
    __shared__ int nbf[KNN];
    int t = threadIdx.x;
    int nf = *nflag;
    for (int f = blockIdx.x; f < nf; f += gridDim.x) {
        int row = flagged[f];
        __syncthreads();
        if (t < D) xr[t] = X[(size_t)row * D + t];
        __syncthreads();
        float sqr = sq[row];
        unsigned long long keys[32];
        for (int i = 0; i < 32; ++i) {
            int col = t + 256 * i;
            const float4* cp = (const float4*)(X + (size_t)col * D);
            float dot = 0.f;
            #pragma unroll
            for (int d4 = 0; d4 < 32; ++d4) {
                float4 c = cp[d4];
                float4 x = *(const float4*)&xr[d4 * 4];
                dot = fmaf(c.x, x.x, dot); dot = fmaf(c.y, x.y, dot);
                dot = fmaf(c.z, x.z, dot); dot = fmaf(c.w, x.w, dot);
            }
            float d2v = fmaxf(sqr + sq[col] - 2.f * dot, 0.f);
            keys[i] = pack_key(d2v, col);
        }
        unsigned long long last = 0ull;
        float sumd = 0.f;
        for (int r = 0; r < KNN; ++r) {
            unsigned long long m = ~0ull;
            #pragma unroll
            for (int i = 0; i < 32; ++i) if (keys[i] > last && keys[i] < m) m = keys[i];
            red[t] = m; __syncthreads();
            for (int s = 128; s; s >>= 1) {
                if (t < s && red[t + s] < red[t]) red[t] = red[t + s];
                __syncthreads();
            }
            m = red[0]; __syncthreads();
            last = m;
            if (t == 0) {
                int j = (int)(m & 16383ull) - 1;
                if (j < 0) j = 0; if (j >= N) j = N - 1;
                knn_idx[(size_t)row * KNN + r] = j;
                nbf[r] = j;
                sumd += sqrtf(__uint_as_float((unsigned)(m >> 14)));
            }
        }
        if (t == 0) density[row] = 1.f / (sumd * (1.f / KNN) + EPS);
        __syncthreads();
        if (t < KNN) {
            int j = nbf[t];
            atomicOr(&bits[(size_t)row * NW + (j >> 5)], 1u << (j & 31));
        }
    }
}

// ---------------- K5b: forward kNN sums (row-owned, zero atomics) ------------
__global__ void k_rowsum(const int* __restrict__ knn_idx, const float* __restrict__ density,
                         float* __restrict__ numer, float* __restrict__ cntb) {
    int i = blockIdx.x * 256 + threadIdx.x;
    if (i >= N) return;
    const int* ki = knn_idx + (size_t)i * KNN;
    float s = 0.f;
    #pragma unroll
    for (int m = 0; m < KNN; ++m) s += density[ki[m]];
    numer[i] = s;
    cntb[i] = (float)KNN;
}

// ---------------- K5c: reverse non-mutual contributions (bitmap test) --------
__global__ void k_rev(const int* __restrict__ knn_idx, const float* __restrict__ density,
                      const unsigned* __restrict__ bits,
                      float* __restrict__ numer, float* __restrict__ cntb) {
    int p = blockIdx.x * 256 + threadIdx.x;
    if (p >= N * KNN) return;
    int i = p / KNN;
    int j = knn_idx[p];
    unsigned wd = bits[(size_t)j * NW + (i >> 5)];
    if (!(wd & (1u << (i & 31)))) {             // i not in knn(j): non-mutual edge
        atomicAdd(&numer[j], density[i]);
        atomicAdd(&cntb[j], 1.f);
    }
}

// ---------------- K6: scores, flags, class preds ----------------
__global__ void k_final(const float* __restrict__ density, const float* __restrict__ numer,
                        const float* __restrict__ cntb, const float* __restrict__ logits,
                        float* __restrict__ out) {
    int i = blockIdx.x * 256 + threadIdx.x;
    if (i >= N) return;
    float c     = fmaxf(cntb[i], 1.f);
    float avg   = numer[i] / c;
    float score = -(density[i] / (avg + EPS));
    out[i] = score;
    bool flag = score < -0.5f;
    out[N + i] = flag ? 1.f : 0.f;
    const float* lg = logits + (size_t)i * NC;
    float best = lg[0]; int bi = 0;
    #pragma unroll
    for (int k = 1; k < NC; ++k) { float x = lg[k]; if (x > best) { best = x; bi = k; } }
    out[2 * N + i] = flag ? -1.f : (float)bi;
}

extern "C" void kernel_launch(void* const* d_in, const int* in_sizes, int n_in,
                              void* d_out, int out_size, void* d_ws, size_t ws_size,
                              hipStream_t stream) {
    const float* X      = (const float*)d_in[0];
    const float* logits = (const float*)d_in[1];
    float* out = (float*)d_out;

    char* w = (char*)d_ws;
    auto alloc = [&](size_t bytes) { char* p = w; w += (bytes + 255) & ~(size_t)255; return p; };
    float* sq      = (float*)alloc((size_t)N * 4);
    float* density = (float*)alloc((size_t)N * 4);
    float* numer   = (float*)alloc((size_t)N * 4);
    float* cntb    = (float*)alloc((size_t)N * 4);
    int*   knn     = (int*)alloc((size_t)N * KNN * 4);
    unsigned short* Xhi = (unsigned short*)alloc((size_t)N * D * 2);
    unsigned short* Xlo = (unsigned short*)alloc((size_t)N * D * 2);
    float* Tthr    = (float*)alloc((size_t)N * 4);
    int*   flagged = (int*)alloc((size_t)N * 4);
    // contiguous zero region: cnt + nflag + m1 (one memset)
    char* zbase    = w;
    int*   cnt     = (int*)alloc((size_t)N * 4);
    int*   nflag   = (int*)alloc(256);
    float* m1      = (float*)alloc((size_t)(D + 2) * 4);
    size_t zsize   = (size_t)(w - zbase);
    unsigned* bits = (unsigned*)alloc((size_t)N * NW * 4);   // 8 MB kNN bitmap

    size_t used  = (size_t)(w - (char*)d_ws);
    size_t avail = ws_size > used ? ws_size - used : 0;
    int capb = (int)(avail / ((size_t)N * 8));
    if (capb > CAPB) capb = CAPB;
    if (capb < 1) capb = 1;                     // degenerate: all rows -> exact fallback
    unsigned long long* rowbuf = (unsigned long long*)alloc((size_t)N * capb * 8);

    hipMemsetAsync(zbase, 0, zsize, stream);
    hipMemsetAsync(bits,  0, (size_t)N * NW * 4, stream);

    k_prep   <<<N, 64, 0, stream>>>(X, Xhi, Xlo, sq);
    k_moments<<<512, 128, 0, stream>>>(X, sq, m1, m1 + D);
    k_thresh <<<N, 64, 0, stream>>>(X, sq, m1, m1 + D, Tthr);

    k_distf3 <<<NBLK, 256, 0, stream>>>(Xhi, Xlo, sq, Tthr, cnt, rowbuf, capb);

    k_sel2    <<<N, 64, 0, stream>>>(rowbuf, cnt, knn, density, bits, flagged, nflag, capb);
    k_fallback<<<64, 256, 0, stream>>>(X, sq, nflag, flagged, knn, density, bits);

    k_rowsum <<<(N + 255) / 256, 256, 0, stream>>>(knn, density, numer, cntb);
    k_rev    <<<(N * KNN + 255) / 256, 256, 0, stream>>>(knn, density, bits, numer, cntb);

    k_final  <<<(N + 255) / 256, 256, 0, stream>>>(density, numer, cntb, logits, out);
}